// Round 3
// baseline (418.812 us; speedup 1.0000x reference)
//
#include <hip/hip_runtime.h>

#define EPSF 1e-5f

// ---------------- helpers ----------------
__device__ __forceinline__ float wred(float v) {
#pragma unroll
  for (int off = 32; off > 0; off >>= 1) v += __shfl_down(v, off, 64);
  return v;
}

// ---------------- conv1: [32,1,20813,3] * [3,1,409,3] s=(6,1) -> [32,3,3401] + stats ----------------
// out[c][oh] = sum_i w[c][i] * mesh[oh*18 + i], i<1227.
// 128 outputs/block; 256 thr = 8 K-chunks x 32 slots; slot owns outputs {s, s+32, s+64, s+96}.
__global__ __launch_bounds__(256) void k_conv1(
    const float* __restrict__ mesh, const float* __restrict__ cw,
    const float* __restrict__ cb, float* __restrict__ out,
    float* __restrict__ part) {
  __shared__ float wsm[3684];   // 3 rows x 1228 (even-padded)
  __shared__ float sm[3513];    // 127*18 + 1227
  __shared__ float red[3072];   // 8 chunks x 384 combos
  __shared__ float pm2[384];
  __shared__ float redm[4][6];
  const int tid = threadIdx.x;
  const int tile = blockIdx.x % 27, b = blockIdx.x / 27;
  const int oh0 = tile << 7;
  const int nvalid = min(128, 3401 - oh0);
  const int nload = (nvalid - 1) * 18 + 1227;
  for (int j = tid; j < 3681; j += 256) {
    int c = (j >= 2454) ? 2 : ((j >= 1227) ? 1 : 0);
    wsm[c * 1228 + (j - c * 1227)] = cw[j];
  }
  const float* src = mesh + b * 62439 + oh0 * 18;
  for (int j = tid; j < nload; j += 256) sm[j] = src[j];
  __syncthreads();
  const int kc = tid >> 5, s = tid & 31;
  const int i0 = kc * 154, i1 = min(1227, i0 + 154);
  float acc[4][3] = {};
  const float* xb = sm + s * 18;
  int i = i0;
#pragma unroll 2
  for (; i + 1 < i1; i += 2) {
    float2 w0 = *(const float2*)(wsm + i);
    float2 w1 = *(const float2*)(wsm + 1228 + i);
    float2 w2 = *(const float2*)(wsm + 2456 + i);
#pragma unroll
    for (int r = 0; r < 4; ++r) {
      float2 x = *(const float2*)(xb + r * 576 + i);
      acc[r][0] = fmaf(w0.x, x.x, fmaf(w0.y, x.y, acc[r][0]));
      acc[r][1] = fmaf(w1.x, x.x, fmaf(w1.y, x.y, acc[r][1]));
      acc[r][2] = fmaf(w2.x, x.x, fmaf(w2.y, x.y, acc[r][2]));
    }
  }
  if (i < i1) {
    float w0 = wsm[i], w1 = wsm[1228 + i], w2 = wsm[2456 + i];
#pragma unroll
    for (int r = 0; r < 4; ++r) {
      float x = xb[r * 576 + i];
      acc[r][0] = fmaf(w0, x, acc[r][0]);
      acc[r][1] = fmaf(w1, x, acc[r][1]);
      acc[r][2] = fmaf(w2, x, acc[r][2]);
    }
  }
#pragma unroll
  for (int r = 0; r < 4; ++r)
#pragma unroll
    for (int ch = 0; ch < 3; ++ch)
      red[kc * 384 + s * 12 + r * 3 + ch] = acc[r][ch];
  __syncthreads();
  float v0 = cb[tid % 3];
#pragma unroll
  for (int c2 = 0; c2 < 8; ++c2) v0 += red[c2 * 384 + tid];
  pm2[tid] = v0;
  if (tid < 128) {
    float v1 = cb[(tid + 256) % 3];
#pragma unroll
    for (int c2 = 0; c2 < 8; ++c2) v1 += red[c2 * 384 + tid + 256];
    pm2[tid + 256] = v1;
  }
  __syncthreads();
  float st[6] = {0.f, 0.f, 0.f, 0.f, 0.f, 0.f};
  if (tid < 128 && tid < nvalid) {
    const int s2 = tid & 31, r2 = tid >> 5;
    float y0 = pm2[s2 * 12 + r2 * 3 + 0];
    float y1 = pm2[s2 * 12 + r2 * 3 + 1];
    float y2 = pm2[s2 * 12 + r2 * 3 + 2];
    float* op = out + b * 10203 + oh0 + tid;
    op[0] = y0; op[3401] = y1; op[6802] = y2;
    st[0] = y0; st[1] = y0 * y0; st[2] = y1; st[3] = y1 * y1; st[4] = y2; st[5] = y2 * y2;
  }
  const int lane = tid & 63, wid = tid >> 6;
#pragma unroll
  for (int c = 0; c < 6; ++c) {
    float rv = wred(st[c]);
    if (lane == 0) redm[wid][c] = rv;
  }
  __syncthreads();
  if (tid < 6)
    part[blockIdx.x * 6 + tid] = redm[0][tid] + redm[1][tid] + redm[2][tid] + redm[3][tid];
}

// ---------------- conv2: bn1(conv1) reshaped, 990-tap stride-3 -> [32,3,3072] + stats ----------------
__global__ __launch_bounds__(256) void k_conv2(
    const float* __restrict__ x1, const float* __restrict__ part1,
    const float* __restrict__ g1, const float* __restrict__ be1,
    const float* __restrict__ cw, const float* __restrict__ cb,
    float* __restrict__ out, float* __restrict__ part) {
  __shared__ float wsm[2976];   // 3 x 992 (even-padded)
  __shared__ float sm[1371];    // 127*3 + 990
  __shared__ float red[3072];
  __shared__ float pm2[384];
  __shared__ float redm[4][6];
  __shared__ float coef[6];
  const int tid = threadIdx.x;
  const int lane = tid & 63, wid = tid >> 6;
  {  // reduce conv1 stats (864 blocks x 6) -> bn1 coefficients
    float r[6] = {0.f, 0.f, 0.f, 0.f, 0.f, 0.f};
    for (int j = tid; j < 864; j += 256) {
#pragma unroll
      for (int c = 0; c < 6; ++c) r[c] += part1[j * 6 + c];
    }
#pragma unroll
    for (int c = 0; c < 6; ++c) {
      float rv = wred(r[c]);
      if (lane == 0) redm[wid][c] = rv;
    }
    __syncthreads();
    if (tid == 0) {
      const float inv_n = 1.f / (32.f * 3401.f);
#pragma unroll
      for (int c = 0; c < 3; ++c) {
        float s = redm[0][2 * c] + redm[1][2 * c] + redm[2][2 * c] + redm[3][2 * c];
        float ss = redm[0][2 * c + 1] + redm[1][2 * c + 1] + redm[2][2 * c + 1] + redm[3][2 * c + 1];
        float m = s * inv_n;
        float var = ss * inv_n - m * m;
        float a = g1[c] * rsqrtf(var + EPSF);
        coef[c] = a; coef[3 + c] = be1[c] - m * a;
      }
    }
  }
  for (int j = tid; j < 2970; j += 256) {
    int c = (j >= 1980) ? 2 : ((j >= 990) ? 1 : 0);
    wsm[c * 992 + (j - c * 990)] = cw[j];
  }
  __syncthreads();  // coef + wsm ready
  const int tile = blockIdx.x % 24, b = blockIdx.x / 24;
  const int oh0 = tile << 7;
  const int g0 = oh0 * 3;
  const float* src = x1 + b * 10203 + g0;
  for (int j = tid; j < 1371; j += 256) {
    int gg = g0 + j;
    int c = (gg >= 6802) ? 2 : ((gg >= 3401) ? 1 : 0);
    sm[j] = fmaf(coef[c], src[j], coef[3 + c]);
  }
  __syncthreads();
  const int kc = tid >> 5, s = tid & 31;
  const int i0 = kc * 124, i1 = min(990, i0 + 124);
  float acc[4][3] = {};
  const float* xb = sm + s * 3;
  int i = i0;
#pragma unroll 2
  for (; i + 1 < i1; i += 2) {
    float2 w0 = *(const float2*)(wsm + i);
    float2 w1 = *(const float2*)(wsm + 992 + i);
    float2 w2 = *(const float2*)(wsm + 1984 + i);
#pragma unroll
    for (int r = 0; r < 4; ++r) {
      float2 x = *(const float2*)(xb + r * 96 + i);
      acc[r][0] = fmaf(w0.x, x.x, fmaf(w0.y, x.y, acc[r][0]));
      acc[r][1] = fmaf(w1.x, x.x, fmaf(w1.y, x.y, acc[r][1]));
      acc[r][2] = fmaf(w2.x, x.x, fmaf(w2.y, x.y, acc[r][2]));
    }
  }
#pragma unroll
  for (int r = 0; r < 4; ++r)
#pragma unroll
    for (int ch = 0; ch < 3; ++ch)
      red[kc * 384 + s * 12 + r * 3 + ch] = acc[r][ch];
  __syncthreads();
  float v0 = cb[tid % 3];
#pragma unroll
  for (int c2 = 0; c2 < 8; ++c2) v0 += red[c2 * 384 + tid];
  pm2[tid] = v0;
  if (tid < 128) {
    float v1 = cb[(tid + 256) % 3];
#pragma unroll
    for (int c2 = 0; c2 < 8; ++c2) v1 += red[c2 * 384 + tid + 256];
    pm2[tid + 256] = v1;
  }
  __syncthreads();
  float st[6] = {0.f, 0.f, 0.f, 0.f, 0.f, 0.f};
  if (tid < 128) {
    const int s2 = tid & 31, r2 = tid >> 5;
    float y0 = pm2[s2 * 12 + r2 * 3 + 0];
    float y1 = pm2[s2 * 12 + r2 * 3 + 1];
    float y2 = pm2[s2 * 12 + r2 * 3 + 2];
    float* op = out + b * 9216 + oh0 + tid;
    op[0] = y0; op[3072] = y1; op[6144] = y2;
    st[0] = y0; st[1] = y0 * y0; st[2] = y1; st[3] = y1 * y1; st[4] = y2; st[5] = y2 * y2;
  }
#pragma unroll
  for (int c = 0; c < 6; ++c) {
    float rv = wred(st[c]);
    if (lane == 0) redm[wid][c] = rv;
  }
  __syncthreads();
  if (tid < 6)
    part[blockIdx.x * 6 + tid] = redm[0][tid] + redm[1][tid] + redm[2][tid] + redm[3][tid];
}

// ---------------- qkv: bn2 + prelu + 3x (9->4) ; q scaled by 1/sqrt(2)*log2(e) ----------------
__global__ __launch_bounds__(256) void k_qkv(
    const float* __restrict__ x2, const float* __restrict__ part2,
    const float* __restrict__ g2, const float* __restrict__ be2,
    const float* __restrict__ pa_p,
    const float* __restrict__ wq, const float* __restrict__ bq,
    const float* __restrict__ wk, const float* __restrict__ bk,
    const float* __restrict__ wv, const float* __restrict__ bv,
    float* __restrict__ qo, float* __restrict__ ko, float* __restrict__ vo) {
  __shared__ float redm[4][6];
  __shared__ float coef[6];
  const int tid = threadIdx.x;
  const int lane = tid & 63, wid = tid >> 6;
  {
    float r[6] = {0.f, 0.f, 0.f, 0.f, 0.f, 0.f};
    for (int j = tid; j < 768; j += 256) {
#pragma unroll
      for (int c = 0; c < 6; ++c) r[c] += part2[j * 6 + c];
    }
#pragma unroll
    for (int c = 0; c < 6; ++c) {
      float rv = wred(r[c]);
      if (lane == 0) redm[wid][c] = rv;
    }
    __syncthreads();
    if (tid == 0) {
      const float inv_n = 1.f / (32.f * 3072.f);
#pragma unroll
      for (int c = 0; c < 3; ++c) {
        float s = redm[0][2 * c] + redm[1][2 * c] + redm[2][2 * c] + redm[3][2 * c];
        float ss = redm[0][2 * c + 1] + redm[1][2 * c + 1] + redm[2][2 * c + 1] + redm[3][2 * c + 1];
        float m = s * inv_n;
        float var = ss * inv_n - m * m;
        float a = g2[c] * rsqrtf(var + EPSF);
        coef[c] = a; coef[3 + c] = be2[c] - m * a;
      }
    }
    __syncthreads();
  }
  const float pa = pa_p[0];
  const int id = blockIdx.x * 256 + tid;
  const int b = id >> 10, f = id & 1023;
  const float* src = x2 + b * 9216 + f * 9;
  float x[9];
  const int z0 = f * 9;
#pragma unroll
  for (int j = 0; j < 9; ++j) {
    int z = z0 + j;
    int c = (z >= 6144) ? 2 : ((z >= 3072) ? 1 : 0);
    float v = fmaf(coef[c], src[j], coef[3 + c]);
    x[j] = (v >= 0.f) ? v : pa * v;
  }
  const float QSCALE = 0.70710678118654752f * 1.44269504088896341f;  // 1/sqrt(HD) * log2(e)
#pragma unroll
  for (int dd = 0; dd < 4; ++dd) {
    float q = bq[dd], k = bk[dd], v = bv[dd];
#pragma unroll
    for (int j = 0; j < 9; ++j) {
      q = fmaf(wq[dd * 9 + j], x[j], q);
      k = fmaf(wk[dd * 9 + j], x[j], k);
      v = fmaf(wv[dd * 9 + j], x[j], v);
    }
    int hh = dd >> 1, d = dd & 1;
    int idx = ((b * 2 + hh) * 1024 + f) * 2 + d;
    qo[idx] = q * QSCALE;
    ko[idx] = k;
    vo[idx] = v;
  }
}

// ---------------- attention: per (b,h) softmax(qk)v, HD=2; bound-max single pass ----------------
__device__ __forceinline__ int kvIdx(int j) { return j + (j >> 7); }

__global__ __launch_bounds__(256) void k_attn(
    const float* __restrict__ q, const float* __restrict__ k,
    const float* __restrict__ v, float* __restrict__ av) {
  __shared__ float4 kv[1032];
  __shared__ float smax[4];
  const int tid = threadIdx.x;
  const int bh = blockIdx.x >> 3, rblk = blockIdx.x & 7;
  const float2* kp = (const float2*)(k + bh * 2048);
  const float2* vp = (const float2*)(v + bh * 2048);
  float nkm = 0.f;
  for (int j = tid; j < 1024; j += 256) {
    float2 kk = kp[j], vv = vp[j];
    kv[kvIdx(j)] = make_float4(kk.x, kk.y, vv.x, vv.y);
    nkm = fmaxf(nkm, fmaf(kk.x, kk.x, kk.y * kk.y));
  }
#pragma unroll
  for (int off = 32; off > 0; off >>= 1) nkm = fmaxf(nkm, __shfl_xor(nkm, off, 64));
  if ((tid & 63) == 0) smax[tid >> 6] = nkm;
  __syncthreads();
  const float knorm = sqrtf(fmaxf(fmaxf(smax[0], smax[1]), fmaxf(smax[2], smax[3])));
  const int lane = tid & 63, w = tid >> 6;
  const int rg = (w << 3) | (lane >> 3);
  const int ks = lane & 7;
  const int r0 = rblk * 128 + rg * 4;
  const float4 q01 = *(const float4*)(q + (bh * 1024 + r0) * 2);
  const float4 q23 = *(const float4*)(q + (bh * 1024 + r0) * 2 + 4);
  float qx[4] = {q01.x, q01.z, q23.x, q23.z};
  float qy[4] = {q01.y, q01.w, q23.y, q23.w};
  float m[4], l[4] = {0.f, 0.f, 0.f, 0.f};
  float o0[4] = {0.f, 0.f, 0.f, 0.f}, o1[4] = {0.f, 0.f, 0.f, 0.f};
#pragma unroll
  for (int r = 0; r < 4; ++r) m[r] = sqrtf(fmaf(qx[r], qx[r], qy[r] * qy[r])) * knorm;
  const int j0 = ks * 128;
#pragma unroll 4
  for (int jj = 0; jj < 128; ++jj) {
    float4 kk = kv[kvIdx(j0 + jj)];
#pragma unroll
    for (int r = 0; r < 4; ++r) {
      float s = fmaf(qx[r], kk.x, qy[r] * kk.y);
      float p = exp2f(s - m[r]);
      l[r] += p;
      o0[r] = fmaf(p, kk.z, o0[r]);
      o1[r] = fmaf(p, kk.w, o1[r]);
    }
  }
#pragma unroll
  for (int off = 1; off <= 4; off <<= 1) {
#pragma unroll
    for (int r = 0; r < 4; ++r) {
      l[r] += __shfl_xor(l[r], off, 64);
      o0[r] += __shfl_xor(o0[r], off, 64);
      o1[r] += __shfl_xor(o1[r], off, 64);
    }
  }
  if (ks == 0) {
    const int b = bh >> 1, hh = bh & 1;
#pragma unroll
    for (int r = 0; r < 4; ++r) {
      float rl = 1.f / l[r];
      *(float2*)(av + b * 4096 + (r0 + r) * 4 + hh * 2) = make_float2(o0[r] * rl, o1[r] * rl);
    }
  }
}

// ---------------- fc: [32,4096] x [1024,4096]^T, K-split partials ----------------
// grid 512 = 16 o-blocks(64) x 32 k-splits(128); thread = 4o x 2b
__global__ __launch_bounds__(256) void k_fc(
    const float* __restrict__ x, const float* __restrict__ w,
    float* __restrict__ pout) {
  __shared__ float xs[128 * 36];
  const int tid = threadIdx.x;
  const int ob = blockIdx.x & 15, ksp = blockIdx.x >> 4;
  const int k0 = ksp * 128, obase = ob * 64;
  for (int r = tid; r < 4096; r += 256) {
    int b = r >> 7, kk = r & 127;
    xs[kk * 36 + b] = x[b * 4096 + k0 + kk];
  }
  __syncthreads();
  const int og = tid & 15, bg = tid >> 4;
  const int o = obase + og * 4, bb0 = bg * 2;
  float acc[4][2] = {};
  const float* wp = w + o * 4096 + k0;
  for (int kk = 0; kk < 128; kk += 4) {
    float2 x0 = *(const float2*)&xs[(kk + 0) * 36 + bb0];
    float2 x1 = *(const float2*)&xs[(kk + 1) * 36 + bb0];
    float2 x2 = *(const float2*)&xs[(kk + 2) * 36 + bb0];
    float2 x3 = *(const float2*)&xs[(kk + 3) * 36 + bb0];
#pragma unroll
    for (int oo = 0; oo < 4; ++oo) {
      float4 wv = *(const float4*)(wp + oo * 4096 + kk);
      acc[oo][0] = fmaf(wv.x, x0.x, fmaf(wv.y, x1.x, fmaf(wv.z, x2.x, fmaf(wv.w, x3.x, acc[oo][0]))));
      acc[oo][1] = fmaf(wv.x, x0.y, fmaf(wv.y, x1.y, fmaf(wv.z, x2.y, fmaf(wv.w, x3.y, acc[oo][1]))));
    }
  }
#pragma unroll
  for (int bi = 0; bi < 2; ++bi) {
    float4 rv = make_float4(acc[0][bi], acc[1][bi], acc[2][bi], acc[3][bi]);
    *(float4*)&pout[(ksp * 32 + bb0 + bi) * 1024 + o] = rv;
  }
}

// ---------------- hred: h[b][o] = fc_b[o] + sum_j p_fc[j][b][o] ----------------
__global__ __launch_bounds__(256) void k_hred(
    const float* __restrict__ pfc, const float* __restrict__ fcb,
    float* __restrict__ h) {
  const int idx = blockIdx.x * 256 + threadIdx.x;
  const int b = idx >> 10, o = idx & 1023;
  float hv = fcb[o];
#pragma unroll 4
  for (int j = 0; j < 32; ++j) hv += pfc[(j * 32 + b) * 1024 + o];
  h[idx] = hv;
}

// ---------------- ff1: [32,1024] x [1024,1024]^T, reads h ----------------
// grid 256 = 16 o-blocks(64) x 16 k-splits(64)
__global__ __launch_bounds__(256) void k_ff1(
    const float* __restrict__ h, const float* __restrict__ w,
    float* __restrict__ pout) {
  __shared__ float xs[64 * 36];
  const int tid = threadIdx.x;
  const int ob = blockIdx.x & 15, ksp = blockIdx.x >> 4;
  const int k0 = ksp * 64, obase = ob * 64;
  for (int r = tid; r < 2048; r += 256) {
    int b = r >> 6, kk = r & 63;
    xs[kk * 36 + b] = h[b * 1024 + k0 + kk];
  }
  __syncthreads();
  const int og = tid & 15, bg = tid >> 4;
  const int o = obase + og * 4, bb0 = bg * 2;
  float acc[4][2] = {};
  const float* wp = w + o * 1024 + k0;
  for (int kk = 0; kk < 64; kk += 4) {
    float2 x0 = *(const float2*)&xs[(kk + 0) * 36 + bb0];
    float2 x1 = *(const float2*)&xs[(kk + 1) * 36 + bb0];
    float2 x2 = *(const float2*)&xs[(kk + 2) * 36 + bb0];
    float2 x3 = *(const float2*)&xs[(kk + 3) * 36 + bb0];
#pragma unroll
    for (int oo = 0; oo < 4; ++oo) {
      float4 wv = *(const float4*)(wp + oo * 1024 + kk);
      acc[oo][0] = fmaf(wv.x, x0.x, fmaf(wv.y, x1.x, fmaf(wv.z, x2.x, fmaf(wv.w, x3.x, acc[oo][0]))));
      acc[oo][1] = fmaf(wv.x, x0.y, fmaf(wv.y, x1.y, fmaf(wv.z, x2.y, fmaf(wv.w, x3.y, acc[oo][1]))));
    }
  }
#pragma unroll
  for (int bi = 0; bi < 2; ++bi) {
    float4 rv = make_float4(acc[0][bi], acc[1][bi], acc[2][bi], acc[3][bi]);
    *(float4*)&pout[(ksp * 32 + bb0 + bi) * 1024 + o] = rv;
  }
}

// ---------------- tail1 (per batch): LN+ELU+residual; ff2; gates; moe stage0 pre-bn ----------------
__global__ __launch_bounds__(256) void k_tail1(
    const float* __restrict__ h, const float* __restrict__ pff1,
    const float* __restrict__ ff1b,
    const float* __restrict__ lng, const float* __restrict__ lnb,
    const float* __restrict__ f2w, const float* __restrict__ f2b,
    const float* __restrict__ vp, const float* __restrict__ w0,
    const float* __restrict__ b0, float* __restrict__ wgate,
    float* __restrict__ s1pre) {
  __shared__ float hs[1024], ts[1024];
  __shared__ float mw_s[48];
  __shared__ float red2[4][2];
  __shared__ float bc[2];
  __shared__ float tot_s;
  const int b = blockIdx.x, tid = threadIdx.x;
  const int lane = tid & 63, wid = tid >> 6;
  for (int o = tid; o < 1024; o += 256) {
    hs[o] = h[b * 1024 + o];
    float tv = ff1b[o];
#pragma unroll 4
    for (int j = 0; j < 16; ++j) tv += pff1[(j * 32 + b) * 1024 + o];
    ts[o] = tv;
  }
  __syncthreads();
  float ls = 0.f, lss = 0.f;
  for (int o = tid; o < 1024; o += 256) {
    float t = ts[o];
    ls += t; lss += t * t;
  }
  ls = wred(ls); lss = wred(lss);
  if (lane == 0) { red2[wid][0] = ls; red2[wid][1] = lss; }
  __syncthreads();
  if (tid == 0) {
    float S = red2[0][0] + red2[1][0] + red2[2][0] + red2[3][0];
    float SS = red2[0][1] + red2[1][1] + red2[2][1] + red2[3][1];
    float m = S * (1.f / 1024.f);
    float var = SS * (1.f / 1024.f) - m * m;
    bc[0] = m; bc[1] = rsqrtf(var + EPSF);
  }
  __syncthreads();
  const float m = bc[0], inv = bc[1];
  for (int o = tid; o < 1024; o += 256) {
    float y = fmaf((ts[o] - m) * inv, lng[o], lnb[o]);
    float e = (y > 0.f) ? y : expm1f(y);
    ts[o] = hs[o] + e;  // h2
  }
  __syncthreads();
  if (tid < 192) {
    int e = tid >> 2, part = tid & 3;
    float acc = 0.f;
    const float* wr = f2w + e * 1024 + part * 4;
    for (int i = 0; i < 64; ++i) {
      float4 wv = *(const float4*)(wr + i * 16);
      int ob = i * 16 + part * 4;
      acc = fmaf(wv.x, ts[ob], fmaf(wv.y, ts[ob + 1], fmaf(wv.z, ts[ob + 2], fmaf(wv.w, ts[ob + 3], acc))));
    }
    acc += __shfl_down(acc, 1, 64);
    acc += __shfl_down(acc, 2, 64);
    if (part == 0) mw_s[e] = acc + f2b[e];
  }
  __syncthreads();
  if (tid < 64) {
    float v = (tid < 48) ? mw_s[tid] : 0.f;
    float t = wred(v);
    if (tid == 0) tot_s = t;
  }
  __syncthreads();
  if (tid < 48) {
    float wg = mw_s[tid] / tot_s;
    mw_s[tid] = wg;
    wgate[b * 48 + tid] = wg;
  }
  __syncthreads();
  if (tid < 32) {
    const int o = tid;
    const float v0 = vp[b * 3], v1 = vp[b * 3 + 1], v2 = vp[b * 3 + 2];
    float acc = 0.f;
#pragma unroll 4
    for (int e = 0; e < 48; ++e) {
      const float* wr = w0 + (e * 32 + o) * 3;
      float y = b0[e * 32 + o] + wr[0] * v0 + wr[1] * v1 + wr[2] * v2;
      acc = fmaf(mw_s[e], y, acc);
    }
    s1pre[b * 32 + o] = acc;
  }
}

// ---------------- moe1 (per batch): bn over batch (redundant) + prelu + gated expert layer 1 ----------------
__global__ __launch_bounds__(128) void k_moe1(
    const float* __restrict__ s1pre, const float* __restrict__ g0,
    const float* __restrict__ be0, const float* __restrict__ pf_p,
    const float* __restrict__ wgate, const float* __restrict__ w1,
    const float* __restrict__ b1, float* __restrict__ s2pre) {
  __shared__ float s1n[32];
  __shared__ float wg[48];
  const int b = blockIdx.x, tid = threadIdx.x;
  const float pf = pf_p[0];
  if (tid < 48) wg[tid] = wgate[b * 48 + tid];
  if (tid < 32) {
    const int o = tid;
    float s = 0.f, ss = 0.f;
    for (int bb = 0; bb < 32; ++bb) {
      float v = s1pre[bb * 32 + o];
      s += v; ss += v * v;
    }
    float mm = s * (1.f / 32.f);
    float var = ss * (1.f / 32.f) - mm * mm;
    float a = g0[o] * rsqrtf(var + EPSF);
    float c = be0[o] - mm * a;
    float v = fmaf(s1pre[b * 32 + o], a, c);
    s1n[o] = (v >= 0.f) ? v : pf * v;
  }
  __syncthreads();
  const int op = tid;
  float acc = 0.f;
  for (int e = 0; e < 48; ++e) {
    const float* wr = w1 + (e * 128 + op) * 32;
    float y = b1[e * 128 + op];
#pragma unroll
    for (int i = 0; i < 32; i += 4) {
      float4 wv = *(const float4*)(wr + i);
      y = fmaf(wv.x, s1n[i], fmaf(wv.y, s1n[i + 1], fmaf(wv.z, s1n[i + 2], fmaf(wv.w, s1n[i + 3], y))));
    }
    acc = fmaf(wg[e], y, acc);
  }
  s2pre[b * 128 + op] = acc;
}

// ---------------- final: bn over batch + prelu + dot(128) + sigmoid ----------------
__global__ __launch_bounds__(256) void k_final(
    const float* __restrict__ s2pre, const float* __restrict__ g1,
    const float* __restrict__ be1, const float* __restrict__ pf_p,
    const float* __restrict__ ow, const float* __restrict__ obp,
    float* __restrict__ outp) {
  __shared__ float s2[32 * 132];
  __shared__ float ca[128], cb[128];
  const int tid = threadIdx.x;
  for (int r = tid; r < 4096; r += 256) {
    int b = r >> 7, o = r & 127;
    s2[b * 132 + o] = s2pre[r];
  }
  __syncthreads();
  if (tid < 128) {
    const int o = tid;
    float s = 0.f, ss = 0.f;
    for (int b = 0; b < 32; ++b) {
      float v = s2[b * 132 + o];
      s += v; ss += v * v;
    }
    float mm = s * (1.f / 32.f);
    float var = ss * (1.f / 32.f) - mm * mm;
    float a = g1[o] * rsqrtf(var + EPSF);
    ca[o] = a; cb[o] = be1[o] - mm * a;
  }
  __syncthreads();
  const float pf = pf_p[0];
  if (tid < 32) {
    const int b = tid;
    float acc = 0.f;
#pragma unroll 4
    for (int o = 0; o < 128; ++o) {
      float v = fmaf(s2[b * 132 + o], ca[o], cb[o]);
      v = (v >= 0.f) ? v : pf * v;
      acc = fmaf(v, ow[o], acc);
    }
    float z = acc + obp[0];
    outp[b] = 1.f / (1.f + __expf(-z));
  }
}

// ---------------- launch ----------------
extern "C" void kernel_launch(void* const* d_in, const int* in_sizes, int n_in,
                              void* d_out, int out_size, void* d_ws, size_t ws_size,
                              hipStream_t stream) {
  (void)in_sizes; (void)n_in; (void)out_size; (void)ws_size;
  const float* vertex_pos = (const float*)d_in[0];
  const float* body_mesh  = (const float*)d_in[1];
  const float* conv1_w    = (const float*)d_in[2];
  const float* conv1_b    = (const float*)d_in[3];
  const float* bn1_g      = (const float*)d_in[4];
  const float* bn1_b      = (const float*)d_in[5];
  const float* conv2_w    = (const float*)d_in[6];
  const float* conv2_b    = (const float*)d_in[7];
  const float* bn2_g      = (const float*)d_in[8];
  const float* bn2_b      = (const float*)d_in[9];
  const float* prelu_a    = (const float*)d_in[10];
  const float* wq = (const float*)d_in[11]; const float* bq = (const float*)d_in[12];
  const float* wk = (const float*)d_in[13]; const float* bk = (const float*)d_in[14];
  const float* wv = (const float*)d_in[15]; const float* bv = (const float*)d_in[16];
  const float* fc_w  = (const float*)d_in[17]; const float* fc_b  = (const float*)d_in[18];
  const float* ff1_w = (const float*)d_in[19]; const float* ff1_b = (const float*)d_in[20];
  const float* ln_g  = (const float*)d_in[21]; const float* ln_b  = (const float*)d_in[22];
  const float* ff2_w = (const float*)d_in[23]; const float* ff2_b = (const float*)d_in[24];
  const float* fus_w0 = (const float*)d_in[25]; const float* fus_b0 = (const float*)d_in[26];
  const float* fus_w1 = (const float*)d_in[27]; const float* fus_b1 = (const float*)d_in[28];
  const float* bnf0_g = (const float*)d_in[29]; const float* bnf0_b = (const float*)d_in[30];
  const float* bnf1_g = (const float*)d_in[31]; const float* bnf1_b = (const float*)d_in[32];
  const float* prelu_f = (const float*)d_in[33];
  const float* out_w = (const float*)d_in[34]; const float* out_b = (const float*)d_in[35];

  float* ws = (float*)d_ws;
  float* conv1_out = ws + 0;        // 326496
  float* conv2_out = ws + 326496;   // -> 621408
  float* qws = ws + 621408;         // -> 752480
  float* kws = ws + 752480;         // -> 883552
  float* vws = ws + 883552;         // -> 1014624
  float* p_fc = ws + 0;             // 1048576 (overlays region A; dead by k_fc)
  float* av    = ws + 1048576;      // -> 1179648
  float* hbuf  = ws + 1179648;      // -> 1212416
  float* p_ff1 = ws + 1212416;      // -> 1736704
  float* part1 = ws + 1736704;      // -> 1741888
  float* part2 = ws + 1741888;      // -> 1746496
  float* wgate = ws + 1746496;      // -> 1748032
  float* s1pre = ws + 1748032;      // -> 1749056
  float* s2pre = ws + 1749056;      // -> 1753152 floats (~7.0 MB)

  k_conv1<<<864, 256, 0, stream>>>(body_mesh, conv1_w, conv1_b, conv1_out, part1);
  k_conv2<<<768, 256, 0, stream>>>(conv1_out, part1, bn1_g, bn1_b, conv2_w, conv2_b, conv2_out, part2);
  k_qkv<<<128, 256, 0, stream>>>(conv2_out, part2, bn2_g, bn2_b, prelu_a,
                                 wq, bq, wk, bk, wv, bv, qws, kws, vws);
  k_attn<<<512, 256, 0, stream>>>(qws, kws, vws, av);
  k_fc<<<512, 256, 0, stream>>>(av, fc_w, p_fc);
  k_hred<<<128, 256, 0, stream>>>(p_fc, fc_b, hbuf);
  k_ff1<<<256, 256, 0, stream>>>(hbuf, ff1_w, p_ff1);
  k_tail1<<<32, 256, 0, stream>>>(hbuf, p_ff1, ff1_b, ln_g, ln_b, ff2_w, ff2_b,
                                  vertex_pos, fus_w0, fus_b0, wgate, s1pre);
  k_moe1<<<32, 128, 0, stream>>>(s1pre, bnf0_g, bnf0_b, prelu_f, wgate, fus_w1, fus_b1, s2pre);
  k_final<<<1, 256, 0, stream>>>(s2pre, bnf1_g, bnf1_b, prelu_f, out_w, out_b, (float*)d_out);
}

// Round 6
// 352.537 us; speedup vs baseline: 1.1880x; 1.1880x over previous
//
#include <hip/hip_runtime.h>

#define EPSF 1e-5f

// ---------------- helpers ----------------
__device__ __forceinline__ float wred(float v) {
#pragma unroll
  for (int off = 32; off > 0; off >>= 1) v += __shfl_down(v, off, 64);
  return v;
}

// ---------------- conv1: [32,1,20813,3] * [3,1,409,3] s=(6,1) -> [32,3,3401] + stats ----------------
// out[c][oh] = sum_i w[c][i] * mesh[oh*18 + i], i<1227.
// 128 outputs/block; 256 thr = 8 K-chunks x 32 slots; slot owns outputs {s, s+32, s+64, s+96}.
__global__ __launch_bounds__(256) void k_conv1(
    const float* __restrict__ mesh, const float* __restrict__ cw,
    const float* __restrict__ cb, float* __restrict__ out,
    float* __restrict__ part) {
  __shared__ float wsm[3684];   // 3 rows x 1228 (even-padded)
  __shared__ float sm[3513];    // 127*18 + 1227
  __shared__ float red[3072];   // 8 chunks x 384 combos
  __shared__ float pm2[384];
  __shared__ float redm[4][6];
  const int tid = threadIdx.x;
  const int tile = blockIdx.x % 27, b = blockIdx.x / 27;
  const int oh0 = tile << 7;
  const int nvalid = min(128, 3401 - oh0);
  const int nload = (nvalid - 1) * 18 + 1227;
  for (int j = tid; j < 3681; j += 256) {
    int c = (j >= 2454) ? 2 : ((j >= 1227) ? 1 : 0);
    wsm[c * 1228 + (j - c * 1227)] = cw[j];
  }
  const float* src = mesh + b * 62439 + oh0 * 18;
  for (int j = tid; j < nload; j += 256) sm[j] = src[j];
  __syncthreads();
  const int kc = tid >> 5, s = tid & 31;
  const int i0 = kc * 154, i1 = min(1227, i0 + 154);
  float acc[4][3] = {};
  const float* xb = sm + s * 18;
  int i = i0;
#pragma unroll 2
  for (; i + 1 < i1; i += 2) {
    float2 w0 = *(const float2*)(wsm + i);
    float2 w1 = *(const float2*)(wsm + 1228 + i);
    float2 w2 = *(const float2*)(wsm + 2456 + i);
#pragma unroll
    for (int r = 0; r < 4; ++r) {
      float2 x = *(const float2*)(xb + r * 576 + i);
      acc[r][0] = fmaf(w0.x, x.x, fmaf(w0.y, x.y, acc[r][0]));
      acc[r][1] = fmaf(w1.x, x.x, fmaf(w1.y, x.y, acc[r][1]));
      acc[r][2] = fmaf(w2.x, x.x, fmaf(w2.y, x.y, acc[r][2]));
    }
  }
  if (i < i1) {
    float w0 = wsm[i], w1 = wsm[1228 + i], w2 = wsm[2456 + i];
#pragma unroll
    for (int r = 0; r < 4; ++r) {
      float x = xb[r * 576 + i];
      acc[r][0] = fmaf(w0, x, acc[r][0]);
      acc[r][1] = fmaf(w1, x, acc[r][1]);
      acc[r][2] = fmaf(w2, x, acc[r][2]);
    }
  }
#pragma unroll
  for (int r = 0; r < 4; ++r)
#pragma unroll
    for (int ch = 0; ch < 3; ++ch)
      red[kc * 384 + s * 12 + r * 3 + ch] = acc[r][ch];
  __syncthreads();
  float v0 = cb[tid % 3];
#pragma unroll
  for (int c2 = 0; c2 < 8; ++c2) v0 += red[c2 * 384 + tid];
  pm2[tid] = v0;
  if (tid < 128) {
    float v1 = cb[(tid + 256) % 3];
#pragma unroll
    for (int c2 = 0; c2 < 8; ++c2) v1 += red[c2 * 384 + tid + 256];
    pm2[tid + 256] = v1;
  }
  __syncthreads();
  float st[6] = {0.f, 0.f, 0.f, 0.f, 0.f, 0.f};
  if (tid < 128 && tid < nvalid) {
    const int s2 = tid & 31, r2 = tid >> 5;
    float y0 = pm2[s2 * 12 + r2 * 3 + 0];
    float y1 = pm2[s2 * 12 + r2 * 3 + 1];
    float y2 = pm2[s2 * 12 + r2 * 3 + 2];
    float* op = out + b * 10203 + oh0 + tid;
    op[0] = y0; op[3401] = y1; op[6802] = y2;
    st[0] = y0; st[1] = y0 * y0; st[2] = y1; st[3] = y1 * y1; st[4] = y2; st[5] = y2 * y2;
  }
  const int lane = tid & 63, wid = tid >> 6;
#pragma unroll
  for (int c = 0; c < 6; ++c) {
    float rv = wred(st[c]);
    if (lane == 0) redm[wid][c] = rv;
  }
  __syncthreads();
  if (tid < 6)
    part[tid * 864 + blockIdx.x] = redm[0][tid] + redm[1][tid] + redm[2][tid] + redm[3][tid];
}

// ---------------- conv2: u-plane decomposition, fully aligned LDS reads ----------------
// out[c][oh] = cb[c] + sum_u sum_{t<330} wT[u][c][t] * P_u[oh+t],  P_u[p] = bn1(x1flat[3p+u]).
// Block: 512 consecutive outputs of one batch; 256 thr = 2 t-chunks x 128 slots;
// slot owns 4 consecutive outputs (float4 rotation window). Weights zero-padded to t<336.
__global__ __launch_bounds__(256) void k_conv2(
    const float* __restrict__ x1, const float* __restrict__ part1,
    const float* __restrict__ g1, const float* __restrict__ be1,
    const float* __restrict__ cw, const float* __restrict__ cb,
    float* __restrict__ out, float* __restrict__ part) {
  __shared__ float wT[3024];      // [u][c][t] rows of 336, zero-padded t>=330
  __shared__ float P[3][852];     // input planes
  __shared__ float red[1536];     // kc1 partials: 128 slots x 12
  __shared__ float redm[4][6];
  __shared__ float coef[6];
  const int tid = threadIdx.x;
  const int lane = tid & 63, wid = tid >> 6;
  {  // reduce conv1 stats (transposed: part1[c*864 + blk]) -> bn1 coefficients
    float r6[6] = {0.f, 0.f, 0.f, 0.f, 0.f, 0.f};
    for (int j = tid; j < 864; j += 256) {
#pragma unroll
      for (int c = 0; c < 6; ++c) r6[c] += part1[c * 864 + j];
    }
#pragma unroll
    for (int c = 0; c < 6; ++c) {
      float rv = wred(r6[c]);
      if (lane == 0) redm[wid][c] = rv;
    }
    __syncthreads();
    if (tid == 0) {
      const float inv_n = 1.f / (32.f * 3401.f);
#pragma unroll
      for (int c = 0; c < 3; ++c) {
        float s = redm[0][2 * c] + redm[1][2 * c] + redm[2][2 * c] + redm[3][2 * c];
        float ss = redm[0][2 * c + 1] + redm[1][2 * c + 1] + redm[2][2 * c + 1] + redm[3][2 * c + 1];
        float m = s * inv_n;
        float var = ss * inv_n - m * m;
        float a = g1[c] * rsqrtf(var + EPSF);
        coef[c] = a; coef[3 + c] = be1[c] - m * a;
      }
    }
  }
  // stage transposed weights: wT[u*1008 + c*336 + t] = cw[c*990 + 3t + u], 0 for t>=330
  for (int j = tid; j < 3024; j += 256) {
    int u = j / 1008, rem = j - u * 1008;
    int c = rem / 336, t = rem - c * 336;
    wT[j] = (t < 330) ? cw[c * 990 + 3 * t + u] : 0.f;
  }
  __syncthreads();  // coef + wT ready
  const int tile = blockIdx.x % 6, b = blockIdx.x / 6;
  const int oh0 = tile << 9;
  const int zbase = oh0 * 3;
  const float* src = x1 + b * 10203 + zbase;
  // stage bn1-transformed planes (coalesced global reads)
  for (int j = tid; j < 2556; j += 256) {
    int rel = j / 3, u = j - rel * 3;
    float val = 0.f;
    int z = zbase + j;
    if (z <= 10202) {
      int c = (z >= 6802) ? 2 : ((z >= 3401) ? 1 : 0);
      val = fmaf(coef[c], src[j], coef[3 + c]);
    }
    P[u][rel] = val;
  }
  __syncthreads();
  const int kc = tid >> 7, s = tid & 127;
  const int t0 = kc * 168;
  const int xb = s << 2;
  float acc0[4] = {}, acc1[4] = {}, acc2[4] = {};
  float4 cur0 = *(const float4*)&P[0][xb + t0];
  float4 cur1 = *(const float4*)&P[1][xb + t0];
  float4 cur2 = *(const float4*)&P[2][xb + t0];
  float4 nxt0 = *(const float4*)&P[0][xb + t0 + 4];
  float4 nxt1 = *(const float4*)&P[1][xb + t0 + 4];
  float4 nxt2 = *(const float4*)&P[2][xb + t0 + 4];
  const int tend = t0 + 168;
  for (int tg = t0; tg < tend; tg += 4) {
#define CONV2_U(ACC0, ACC1, ACC2, UOFF, CUR, NXT)                                                  \
    {                                                                                              \
      const float* wu = wT + UOFF + tg;                                                            \
      float2 wa0 = *(const float2*)(wu);                                                           \
      float2 wb0 = *(const float2*)(wu + 2);                                                       \
      float2 wa1 = *(const float2*)(wu + 336);                                                     \
      float2 wb1 = *(const float2*)(wu + 338);                                                     \
      float2 wa2 = *(const float2*)(wu + 672);                                                     \
      float2 wb2 = *(const float2*)(wu + 674);                                                     \
      float x0 = CUR.x, x1v = CUR.y, x2v = CUR.z, x3v = CUR.w;                                     \
      float x4 = NXT.x, x5 = NXT.y, x6 = NXT.z;                                                    \
      ACC0[0] = fmaf(wa0.x, x0,  fmaf(wa0.y, x1v, fmaf(wb0.x, x2v, fmaf(wb0.y, x3v, ACC0[0]))));  \
      ACC0[1] = fmaf(wa0.x, x1v, fmaf(wa0.y, x2v, fmaf(wb0.x, x3v, fmaf(wb0.y, x4,  ACC0[1]))));  \
      ACC0[2] = fmaf(wa0.x, x2v, fmaf(wa0.y, x3v, fmaf(wb0.x, x4,  fmaf(wb0.y, x5,  ACC0[2]))));  \
      ACC0[3] = fmaf(wa0.x, x3v, fmaf(wa0.y, x4,  fmaf(wb0.x, x5,  fmaf(wb0.y, x6,  ACC0[3]))));  \
      ACC1[0] = fmaf(wa1.x, x0,  fmaf(wa1.y, x1v, fmaf(wb1.x, x2v, fmaf(wb1.y, x3v, ACC1[0]))));  \
      ACC1[1] = fmaf(wa1.x, x1v, fmaf(wa1.y, x2v, fmaf(wb1.x, x3v, fmaf(wb1.y, x4,  ACC1[1]))));  \
      ACC1[2] = fmaf(wa1.x, x2v, fmaf(wa1.y, x3v, fmaf(wb1.x, x4,  fmaf(wb1.y, x5,  ACC1[2]))));  \
      ACC1[3] = fmaf(wa1.x, x3v, fmaf(wa1.y, x4,  fmaf(wb1.x, x5,  fmaf(wb1.y, x6,  ACC1[3]))));  \
      ACC2[0] = fmaf(wa2.x, x0,  fmaf(wa2.y, x1v, fmaf(wb2.x, x2v, fmaf(wb2.y, x3v, ACC2[0]))));  \
      ACC2[1] = fmaf(wa2.x, x1v, fmaf(wa2.y, x2v, fmaf(wb2.x, x3v, fmaf(wb2.y, x4,  ACC2[1]))));  \
      ACC2[2] = fmaf(wa2.x, x2v, fmaf(wa2.y, x3v, fmaf(wb2.x, x4,  fmaf(wb2.y, x5,  ACC2[2]))));  \
      ACC2[3] = fmaf(wa2.x, x3v, fmaf(wa2.y, x4,  fmaf(wb2.x, x5,  fmaf(wb2.y, x6,  ACC2[3]))));  \
    }
    CONV2_U(acc0, acc1, acc2, 0,    cur0, nxt0)
    CONV2_U(acc0, acc1, acc2, 1008, cur1, nxt1)
    CONV2_U(acc0, acc1, acc2, 2016, cur2, nxt2)
#undef CONV2_U
    cur0 = nxt0; cur1 = nxt1; cur2 = nxt2;
    nxt0 = *(const float4*)&P[0][xb + tg + 8];
    nxt1 = *(const float4*)&P[1][xb + tg + 8];
    nxt2 = *(const float4*)&P[2][xb + tg + 8];
  }
  if (kc == 1) {
#pragma unroll
    for (int r = 0; r < 4; ++r) {
      red[s * 12 + r] = acc0[r];
      red[s * 12 + 4 + r] = acc1[r];
      red[s * 12 + 8 + r] = acc2[r];
    }
  }
  __syncthreads();
  float st[6] = {0.f, 0.f, 0.f, 0.f, 0.f, 0.f};
  if (kc == 0) {
    float y0[4], y1[4], y2[4];
#pragma unroll
    for (int r = 0; r < 4; ++r) {
      y0[r] = acc0[r] + red[s * 12 + r] + cb[0];
      y1[r] = acc1[r] + red[s * 12 + 4 + r] + cb[1];
      y2[r] = acc2[r] + red[s * 12 + 8 + r] + cb[2];
      st[0] += y0[r]; st[1] += y0[r] * y0[r];
      st[2] += y1[r]; st[3] += y1[r] * y1[r];
      st[4] += y2[r]; st[5] += y2[r] * y2[r];
    }
    float* op = out + b * 9216 + oh0 + xb;
    *(float4*)(op)        = make_float4(y0[0], y0[1], y0[2], y0[3]);
    *(float4*)(op + 3072) = make_float4(y1[0], y1[1], y1[2], y1[3]);
    *(float4*)(op + 6144) = make_float4(y2[0], y2[1], y2[2], y2[3]);
  }
#pragma unroll
  for (int c = 0; c < 6; ++c) {
    float rv = wred(st[c]);
    if (lane == 0) redm[wid][c] = rv;
  }
  __syncthreads();
  if (tid < 6)
    part[tid * 192 + blockIdx.x] = redm[0][tid] + redm[1][tid] + redm[2][tid] + redm[3][tid];
}

// ---------------- qkv: bn2 + prelu + 3x (9->4) ; q scaled by 1/sqrt(2)*log2(e) ----------------
__global__ __launch_bounds__(256) void k_qkv(
    const float* __restrict__ x2, const float* __restrict__ part2,
    const float* __restrict__ g2, const float* __restrict__ be2,
    const float* __restrict__ pa_p,
    const float* __restrict__ wq, const float* __restrict__ bq,
    const float* __restrict__ wk, const float* __restrict__ bk,
    const float* __restrict__ wv, const float* __restrict__ bv,
    float* __restrict__ qo, float* __restrict__ ko, float* __restrict__ vo) {
  __shared__ float redm[4][6];
  __shared__ float coef[6];
  const int tid = threadIdx.x;
  const int lane = tid & 63, wid = tid >> 6;
  {
    float r[6] = {0.f, 0.f, 0.f, 0.f, 0.f, 0.f};
    for (int j = tid; j < 192; j += 256) {
#pragma unroll
      for (int c = 0; c < 6; ++c) r[c] += part2[c * 192 + j];
    }
#pragma unroll
    for (int c = 0; c < 6; ++c) {
      float rv = wred(r[c]);
      if (lane == 0) redm[wid][c] = rv;
    }
    __syncthreads();
    if (tid == 0) {
      const float inv_n = 1.f / (32.f * 3072.f);
#pragma unroll
      for (int c = 0; c < 3; ++c) {
        float s = redm[0][2 * c] + redm[1][2 * c] + redm[2][2 * c] + redm[3][2 * c];
        float ss = redm[0][2 * c + 1] + redm[1][2 * c + 1] + redm[2][2 * c + 1] + redm[3][2 * c + 1];
        float m = s * inv_n;
        float var = ss * inv_n - m * m;
        float a = g2[c] * rsqrtf(var + EPSF);
        coef[c] = a; coef[3 + c] = be2[c] - m * a;
      }
    }
    __syncthreads();
  }
  const float pa = pa_p[0];
  const int id = blockIdx.x * 256 + tid;
  const int b = id >> 10, f = id & 1023;
  const float* src = x2 + b * 9216 + f * 9;
  float x[9];
  const int z0 = f * 9;
#pragma unroll
  for (int j = 0; j < 9; ++j) {
    int z = z0 + j;
    int c = (z >= 6144) ? 2 : ((z >= 3072) ? 1 : 0);
    float v = fmaf(coef[c], src[j], coef[3 + c]);
    x[j] = (v >= 0.f) ? v : pa * v;
  }
  const float QSCALE = 0.70710678118654752f * 1.44269504088896341f;  // 1/sqrt(HD) * log2(e)
#pragma unroll
  for (int dd = 0; dd < 4; ++dd) {
    float q = bq[dd], k = bk[dd], v = bv[dd];
#pragma unroll
    for (int j = 0; j < 9; ++j) {
      q = fmaf(wq[dd * 9 + j], x[j], q);
      k = fmaf(wk[dd * 9 + j], x[j], k);
      v = fmaf(wv[dd * 9 + j], x[j], v);
    }
    int hh = dd >> 1, d = dd & 1;
    int idx = ((b * 2 + hh) * 1024 + f) * 2 + d;
    qo[idx] = q * QSCALE;
    ko[idx] = k;
    vo[idx] = v;
  }
}

// ---------------- attention: per (b,h) softmax(qk)v, HD=2; bound-max single pass ----------------
__device__ __forceinline__ int kvIdx(int j) { return j + (j >> 7); }

__global__ __launch_bounds__(256) void k_attn(
    const float* __restrict__ q, const float* __restrict__ k,
    const float* __restrict__ v, float* __restrict__ av) {
  __shared__ float4 kv[1032];
  __shared__ float smax[4];
  const int tid = threadIdx.x;
  const int bh = blockIdx.x >> 3, rblk = blockIdx.x & 7;
  const float2* kp = (const float2*)(k + bh * 2048);
  const float2* vp = (const float2*)(v + bh * 2048);
  float nkm = 0.f;
  for (int j = tid; j < 1024; j += 256) {
    float2 kk = kp[j], vv = vp[j];
    kv[kvIdx(j)] = make_float4(kk.x, kk.y, vv.x, vv.y);
    nkm = fmaxf(nkm, fmaf(kk.x, kk.x, kk.y * kk.y));
  }
#pragma unroll
  for (int off = 32; off > 0; off >>= 1) nkm = fmaxf(nkm, __shfl_xor(nkm, off, 64));
  if ((tid & 63) == 0) smax[tid >> 6] = nkm;
  __syncthreads();
  const float knorm = sqrtf(fmaxf(fmaxf(smax[0], smax[1]), fmaxf(smax[2], smax[3])));
  const int lane = tid & 63, w = tid >> 6;
  const int rg = (w << 3) | (lane >> 3);
  const int ks = lane & 7;
  const int r0 = rblk * 128 + rg * 4;
  const float4 q01 = *(const float4*)(q + (bh * 1024 + r0) * 2);
  const float4 q23 = *(const float4*)(q + (bh * 1024 + r0) * 2 + 4);
  float qx[4] = {q01.x, q01.z, q23.x, q23.z};
  float qy[4] = {q01.y, q01.w, q23.y, q23.w};
  float m[4], l[4] = {0.f, 0.f, 0.f, 0.f};
  float o0[4] = {0.f, 0.f, 0.f, 0.f}, o1[4] = {0.f, 0.f, 0.f, 0.f};
#pragma unroll
  for (int r = 0; r < 4; ++r) m[r] = sqrtf(fmaf(qx[r], qx[r], qy[r] * qy[r])) * knorm;
  const int j0 = ks * 128;
#pragma unroll 4
  for (int jj = 0; jj < 128; ++jj) {
    float4 kk = kv[kvIdx(j0 + jj)];
#pragma unroll
    for (int r = 0; r < 4; ++r) {
      float s = fmaf(qx[r], kk.x, qy[r] * kk.y);
      float p = exp2f(s - m[r]);
      l[r] += p;
      o0[r] = fmaf(p, kk.z, o0[r]);
      o1[r] = fmaf(p, kk.w, o1[r]);
    }
  }
#pragma unroll
  for (int off = 1; off <= 4; off <<= 1) {
#pragma unroll
    for (int r = 0; r < 4; ++r) {
      l[r] += __shfl_xor(l[r], off, 64);
      o0[r] += __shfl_xor(o0[r], off, 64);
      o1[r] += __shfl_xor(o1[r], off, 64);
    }
  }
  if (ks == 0) {
    const int b = bh >> 1, hh = bh & 1;
#pragma unroll
    for (int r = 0; r < 4; ++r) {
      float rl = 1.f / l[r];
      *(float2*)(av + b * 4096 + (r0 + r) * 4 + hh * 2) = make_float2(o0[r] * rl, o1[r] * rl);
    }
  }
}

// ---------------- fc: [32,4096] x [1024,4096]^T, K-split partials ----------------
// grid 512 = 16 o-blocks(64) x 32 k-splits(128); thread = 4o x 2b
__global__ __launch_bounds__(256) void k_fc(
    const float* __restrict__ x, const float* __restrict__ w,
    float* __restrict__ pout) {
  __shared__ float xs[128 * 36];
  const int tid = threadIdx.x;
  const int ob = blockIdx.x & 15, ksp = blockIdx.x >> 4;
  const int k0 = ksp * 128, obase = ob * 64;
  for (int r = tid; r < 4096; r += 256) {
    int b = r >> 7, kk = r & 127;
    xs[kk * 36 + b] = x[b * 4096 + k0 + kk];
  }
  __syncthreads();
  const int og = tid & 15, bg = tid >> 4;
  const int o = obase + og * 4, bb0 = bg * 2;
  float acc[4][2] = {};
  const float* wp = w + o * 4096 + k0;
  for (int kk = 0; kk < 128; kk += 4) {
    float2 x0 = *(const float2*)&xs[(kk + 0) * 36 + bb0];
    float2 x1 = *(const float2*)&xs[(kk + 1) * 36 + bb0];
    float2 x2 = *(const float2*)&xs[(kk + 2) * 36 + bb0];
    float2 x3 = *(const float2*)&xs[(kk + 3) * 36 + bb0];
#pragma unroll
    for (int oo = 0; oo < 4; ++oo) {
      float4 wv = *(const float4*)(wp + oo * 4096 + kk);
      acc[oo][0] = fmaf(wv.x, x0.x, fmaf(wv.y, x1.x, fmaf(wv.z, x2.x, fmaf(wv.w, x3.x, acc[oo][0]))));
      acc[oo][1] = fmaf(wv.x, x0.y, fmaf(wv.y, x1.y, fmaf(wv.z, x2.y, fmaf(wv.w, x3.y, acc[oo][1]))));
    }
  }
#pragma unroll
  for (int bi = 0; bi < 2; ++bi) {
    float4 rv = make_float4(acc[0][bi], acc[1][bi], acc[2][bi], acc[3][bi]);
    *(float4*)&pout[(ksp * 32 + bb0 + bi) * 1024 + o] = rv;
  }
}

// ---------------- hred: h[b][o] = fc_b[o] + sum_j p_fc[j][b][o] ----------------
__global__ __launch_bounds__(256) void k_hred(
    const float* __restrict__ pfc, const float* __restrict__ fcb,
    float* __restrict__ h) {
  const int idx = blockIdx.x * 256 + threadIdx.x;
  const int b = idx >> 10, o = idx & 1023;
  float hv = fcb[o];
#pragma unroll 4
  for (int j = 0; j < 32; ++j) hv += pfc[(j * 32 + b) * 1024 + o];
  h[idx] = hv;
}

// ---------------- ff1: [32,1024] x [1024,1024]^T, reads h ----------------
// grid 256 = 16 o-blocks(64) x 16 k-splits(64)
__global__ __launch_bounds__(256) void k_ff1(
    const float* __restrict__ h, const float* __restrict__ w,
    float* __restrict__ pout) {
  __shared__ float xs[64 * 36];
  const int tid = threadIdx.x;
  const int ob = blockIdx.x & 15, ksp = blockIdx.x >> 4;
  const int k0 = ksp * 64, obase = ob * 64;
  for (int r = tid; r < 2048; r += 256) {
    int b = r >> 6, kk = r & 63;
    xs[kk * 36 + b] = h[b * 1024 + k0 + kk];
  }
  __syncthreads();
  const int og = tid & 15, bg = tid >> 4;
  const int o = obase + og * 4, bb0 = bg * 2;
  float acc[4][2] = {};
  const float* wp = w + o * 1024 + k0;
  for (int kk = 0; kk < 64; kk += 4) {
    float2 x0 = *(const float2*)&xs[(kk + 0) * 36 + bb0];
    float2 x1 = *(const float2*)&xs[(kk + 1) * 36 + bb0];
    float2 x2 = *(const float2*)&xs[(kk + 2) * 36 + bb0];
    float2 x3 = *(const float2*)&xs[(kk + 3) * 36 + bb0];
#pragma unroll
    for (int oo = 0; oo < 4; ++oo) {
      float4 wv = *(const float4*)(wp + oo * 1024 + kk);
      acc[oo][0] = fmaf(wv.x, x0.x, fmaf(wv.y, x1.x, fmaf(wv.z, x2.x, fmaf(wv.w, x3.x, acc[oo][0]))));
      acc[oo][1] = fmaf(wv.x, x0.y, fmaf(wv.y, x1.y, fmaf(wv.z, x2.y, fmaf(wv.w, x3.y, acc[oo][1]))));
    }
  }
#pragma unroll
  for (int bi = 0; bi < 2; ++bi) {
    float4 rv = make_float4(acc[0][bi], acc[1][bi], acc[2][bi], acc[3][bi]);
    *(float4*)&pout[(ksp * 32 + bb0 + bi) * 1024 + o] = rv;
  }
}

// ---------------- tail1 (per batch): LN+ELU+residual; ff2; gates; moe stage0 pre-bn ----------------
__global__ __launch_bounds__(256) void k_tail1(
    const float* __restrict__ h, const float* __restrict__ pff1,
    const float* __restrict__ ff1b,
    const float* __restrict__ lng, const float* __restrict__ lnb,
    const float* __restrict__ f2w, const float* __restrict__ f2b,
    const float* __restrict__ vp, const float* __restrict__ w0,
    const float* __restrict__ b0, float* __restrict__ wgate,
    float* __restrict__ s1pre) {
  __shared__ float hs[1024], ts[1024];
  __shared__ float mw_s[48];
  __shared__ float red2[4][2];
  __shared__ float bc[2];
  __shared__ float tot_s;
  const int b = blockIdx.x, tid = threadIdx.x;
  const int lane = tid & 63, wid = tid >> 6;
  for (int o = tid; o < 1024; o += 256) {
    hs[o] = h[b * 1024 + o];
    float tv = ff1b[o];
#pragma unroll 4
    for (int j = 0; j < 16; ++j) tv += pff1[(j * 32 + b) * 1024 + o];
    ts[o] = tv;
  }
  __syncthreads();
  float ls = 0.f, lss = 0.f;
  for (int o = tid; o < 1024; o += 256) {
    float t = ts[o];
    ls += t; lss += t * t;
  }
  ls = wred(ls); lss = wred(lss);
  if (lane == 0) { red2[wid][0] = ls; red2[wid][1] = lss; }
  __syncthreads();
  if (tid == 0) {
    float S = red2[0][0] + red2[1][0] + red2[2][0] + red2[3][0];
    float SS = red2[0][1] + red2[1][1] + red2[2][1] + red2[3][1];
    float m = S * (1.f / 1024.f);
    float var = SS * (1.f / 1024.f) - m * m;
    bc[0] = m; bc[1] = rsqrtf(var + EPSF);
  }
  __syncthreads();
  const float m = bc[0], inv = bc[1];
  for (int o = tid; o < 1024; o += 256) {
    float y = fmaf((ts[o] - m) * inv, lng[o], lnb[o]);
    float e = (y > 0.f) ? y : expm1f(y);
    ts[o] = hs[o] + e;  // h2
  }
  __syncthreads();
  if (tid < 192) {
    int e = tid >> 2, part = tid & 3;
    float acc = 0.f;
    const float* wr = f2w + e * 1024 + part * 4;
    for (int i = 0; i < 64; ++i) {
      float4 wv = *(const float4*)(wr + i * 16);
      int ob = i * 16 + part * 4;
      acc = fmaf(wv.x, ts[ob], fmaf(wv.y, ts[ob + 1], fmaf(wv.z, ts[ob + 2], fmaf(wv.w, ts[ob + 3], acc))));
    }
    acc += __shfl_down(acc, 1, 64);
    acc += __shfl_down(acc, 2, 64);
    if (part == 0) mw_s[e] = acc + f2b[e];
  }
  __syncthreads();
  if (tid < 64) {
    float v = (tid < 48) ? mw_s[tid] : 0.f;
    float t = wred(v);
    if (tid == 0) tot_s = t;
  }
  __syncthreads();
  if (tid < 48) {
    float wg = mw_s[tid] / tot_s;
    mw_s[tid] = wg;
    wgate[b * 48 + tid] = wg;
  }
  __syncthreads();
  if (tid < 32) {
    const int o = tid;
    const float v0 = vp[b * 3], v1 = vp[b * 3 + 1], v2 = vp[b * 3 + 2];
    float acc = 0.f;
#pragma unroll 4
    for (int e = 0; e < 48; ++e) {
      const float* wr = w0 + (e * 32 + o) * 3;
      float y = b0[e * 32 + o] + wr[0] * v0 + wr[1] * v1 + wr[2] * v2;
      acc = fmaf(mw_s[e], y, acc);
    }
    s1pre[b * 32 + o] = acc;
  }
}

// ---------------- moe1 (per batch): bn over batch (redundant) + prelu + gated expert layer 1 ----------------
__global__ __launch_bounds__(128) void k_moe1(
    const float* __restrict__ s1pre, const float* __restrict__ g0,
    const float* __restrict__ be0, const float* __restrict__ pf_p,
    const float* __restrict__ wgate, const float* __restrict__ w1,
    const float* __restrict__ b1, float* __restrict__ s2pre) {
  __shared__ float s1n[32];
  __shared__ float wg[48];
  const int b = blockIdx.x, tid = threadIdx.x;
  const float pf = pf_p[0];
  if (tid < 48) wg[tid] = wgate[b * 48 + tid];
  if (tid < 32) {
    const int o = tid;
    float s = 0.f, ss = 0.f;
    for (int bb = 0; bb < 32; ++bb) {
      float v = s1pre[bb * 32 + o];
      s += v; ss += v * v;
    }
    float mm = s * (1.f / 32.f);
    float var = ss * (1.f / 32.f) - mm * mm;
    float a = g0[o] * rsqrtf(var + EPSF);
    float c = be0[o] - mm * a;
    float v = fmaf(s1pre[b * 32 + o], a, c);
    s1n[o] = (v >= 0.f) ? v : pf * v;
  }
  __syncthreads();
  const int op = tid;
  float acc = 0.f;
  for (int e = 0; e < 48; ++e) {
    const float* wr = w1 + (e * 128 + op) * 32;
    float y = b1[e * 128 + op];
#pragma unroll
    for (int i = 0; i < 32; i += 4) {
      float4 wv = *(const float4*)(wr + i);
      y = fmaf(wv.x, s1n[i], fmaf(wv.y, s1n[i + 1], fmaf(wv.z, s1n[i + 2], fmaf(wv.w, s1n[i + 3], y))));
    }
    acc = fmaf(wg[e], y, acc);
  }
  s2pre[b * 128 + op] = acc;
}

// ---------------- final: bn over batch + prelu + dot(128) + sigmoid ----------------
__global__ __launch_bounds__(256) void k_final(
    const float* __restrict__ s2pre, const float* __restrict__ g1,
    const float* __restrict__ be1, const float* __restrict__ pf_p,
    const float* __restrict__ ow, const float* __restrict__ obp,
    float* __restrict__ outp) {
  __shared__ float s2[32 * 132];
  __shared__ float ca[128], cb[128];
  const int tid = threadIdx.x;
  for (int r = tid; r < 4096; r += 256) {
    int b = r >> 7, o = r & 127;
    s2[b * 132 + o] = s2pre[r];
  }
  __syncthreads();
  if (tid < 128) {
    const int o = tid;
    float s = 0.f, ss = 0.f;
    for (int b = 0; b < 32; ++b) {
      float v = s2[b * 132 + o];
      s += v; ss += v * v;
    }
    float mm = s * (1.f / 32.f);
    float var = ss * (1.f / 32.f) - mm * mm;
    float a = g1[o] * rsqrtf(var + EPSF);
    ca[o] = a; cb[o] = be1[o] - mm * a;
  }
  __syncthreads();
  const float pf = pf_p[0];
  if (tid < 32) {
    const int b = tid;
    float acc = 0.f;
#pragma unroll 4
    for (int o = 0; o < 128; ++o) {
      float v = fmaf(s2[b * 132 + o], ca[o], cb[o]);
      v = (v >= 0.f) ? v : pf * v;
      acc = fmaf(v, ow[o], acc);
    }
    float z = acc + obp[0];
    outp[b] = 1.f / (1.f + __expf(-z));
  }
}

// ---------------- launch ----------------
extern "C" void kernel_launch(void* const* d_in, const int* in_sizes, int n_in,
                              void* d_out, int out_size, void* d_ws, size_t ws_size,
                              hipStream_t stream) {
  (void)in_sizes; (void)n_in; (void)out_size; (void)ws_size;
  const float* vertex_pos = (const float*)d_in[0];
  const float* body_mesh  = (const float*)d_in[1];
  const float* conv1_w    = (const float*)d_in[2];
  const float* conv1_b    = (const float*)d_in[3];
  const float* bn1_g      = (const float*)d_in[4];
  const float* bn1_b      = (const float*)d_in[5];
  const float* conv2_w    = (const float*)d_in[6];
  const float* conv2_b    = (const float*)d_in[7];
  const float* bn2_g      = (const float*)d_in[8];
  const float* bn2_b      = (const float*)d_in[9];
  const float* prelu_a    = (const float*)d_in[10];
  const float* wq = (const float*)d_in[11]; const float* bq = (const float*)d_in[12];
  const float* wk = (const float*)d_in[13]; const float* bk = (const float*)d_in[14];
  const float* wv = (const float*)d_in[15]; const float* bv = (const float*)d_in[16];
  const float* fc_w  = (const float*)d_in[17]; const float* fc_b  = (const float*)d_in[18];
  const float* ff1_w = (const float*)d_in[19]; const float* ff1_b = (const float*)d_in[20];
  const float* ln_g  = (const float*)d_in[21]; const float* ln_b  = (const float*)d_in[22];
  const float* ff2_w = (const float*)d_in[23]; const float* ff2_b = (const float*)d_in[24];
  const float* fus_w0 = (const float*)d_in[25]; const float* fus_b0 = (const float*)d_in[26];
  const float* fus_w1 = (const float*)d_in[27]; const float* fus_b1 = (const float*)d_in[28];
  const float* bnf0_g = (const float*)d_in[29]; const float* bnf0_b = (const float*)d_in[30];
  const float* bnf1_g = (const float*)d_in[31]; const float* bnf1_b = (const float*)d_in[32];
  const float* prelu_f = (const float*)d_in[33];
  const float* out_w = (const float*)d_in[34]; const float* out_b = (const float*)d_in[35];

  float* ws = (float*)d_ws;
  float* conv1_out = ws + 0;        // 326496
  float* conv2_out = ws + 326496;   // -> 621408
  float* qws = ws + 621408;         // -> 752480
  float* kws = ws + 752480;         // -> 883552
  float* vws = ws + 883552;         // -> 1014624
  float* p_fc = ws + 0;             // 1048576 (overlays region A; dead by k_fc)
  float* av    = ws + 1048576;      // -> 1179648
  float* hbuf  = ws + 1179648;      // -> 1212416
  float* p_ff1 = ws + 1212416;      // -> 1736704
  float* part1 = ws + 1736704;      // 6*864 -> 1741888
  float* part2 = ws + 1741888;      // 6*192 -> 1746496
  float* wgate = ws + 1746496;      // -> 1748032
  float* s1pre = ws + 1748032;      // -> 1749056
  float* s2pre = ws + 1749056;      // -> 1753152 floats (~7.0 MB)

  k_conv1<<<864, 256, 0, stream>>>(body_mesh, conv1_w, conv1_b, conv1_out, part1);
  k_conv2<<<192, 256, 0, stream>>>(conv1_out, part1, bn1_g, bn1_b, conv2_w, conv2_b, conv2_out, part2);
  k_qkv<<<128, 256, 0, stream>>>(conv2_out, part2, bn2_g, bn2_b, prelu_a,
                                 wq, bq, wk, bk, wv, bv, qws, kws, vws);
  k_attn<<<512, 256, 0, stream>>>(qws, kws, vws, av);
  k_fc<<<512, 256, 0, stream>>>(av, fc_w, p_fc);
  k_hred<<<128, 256, 0, stream>>>(p_fc, fc_b, hbuf);
  k_ff1<<<256, 256, 0, stream>>>(hbuf, ff1_w, p_ff1);
  k_tail1<<<32, 256, 0, stream>>>(hbuf, p_ff1, ff1_b, ln_g, ln_b, ff2_w, ff2_b,
                                  vertex_pos, fus_w0, fus_b0, wgate, s1pre);
  k_moe1<<<32, 128, 0, stream>>>(s1pre, bnf0_g, bnf0_b, prelu_f, wgate, fus_w1, fus_b1, s2pre);
  k_final<<<1, 256, 0, stream>>>(s2pre, bnf1_g, bnf1_b, prelu_f, out_w, out_b, (float*)d_out);
}

// Round 7
// 325.004 us; speedup vs baseline: 1.2886x; 1.0847x over previous
//
#include <hip/hip_runtime.h>

#define EPSF 1e-5f

// ---------------- helpers ----------------
__device__ __forceinline__ float wred(float v) {
#pragma unroll
  for (int off = 32; off > 0; off >>= 1) v += __shfl_down(v, off, 64);
  return v;
}

// ---------------- conv1: [32,1,20813,3] * [3,1,409,3] s=(6,1) -> [32,3,3401] + stats ----------------
// out[c][oh] = sum_i w[c][i] * mesh[oh*18 + i], i<1227.
// 128 outputs/block; 256 thr = 8 K-chunks x 32 slots; slot owns outputs {s, s+32, s+64, s+96}.
__global__ __launch_bounds__(256) void k_conv1(
    const float* __restrict__ mesh, const float* __restrict__ cw,
    const float* __restrict__ cb, float* __restrict__ out,
    float* __restrict__ part) {
  __shared__ float wsm[3684];   // 3 rows x 1228 (even-padded)
  __shared__ float sm[3513];    // 127*18 + 1227
  __shared__ float red[3072];   // 8 chunks x 384 combos
  __shared__ float pm2[384];
  __shared__ float redm[4][6];
  const int tid = threadIdx.x;
  const int tile = blockIdx.x % 27, b = blockIdx.x / 27;
  const int oh0 = tile << 7;
  const int nvalid = min(128, 3401 - oh0);
  const int nload = (nvalid - 1) * 18 + 1227;
  for (int j = tid; j < 3681; j += 256) {
    int c = (j >= 2454) ? 2 : ((j >= 1227) ? 1 : 0);
    wsm[c * 1228 + (j - c * 1227)] = cw[j];
  }
  const float* src = mesh + b * 62439 + oh0 * 18;
  for (int j = tid; j < nload; j += 256) sm[j] = src[j];
  __syncthreads();
  const int kc = tid >> 5, s = tid & 31;
  const int i0 = kc * 154, i1 = min(1227, i0 + 154);
  float acc[4][3] = {};
  const float* xb = sm + s * 18;
  int i = i0;
#pragma unroll 2
  for (; i + 1 < i1; i += 2) {
    float2 w0 = *(const float2*)(wsm + i);
    float2 w1 = *(const float2*)(wsm + 1228 + i);
    float2 w2 = *(const float2*)(wsm + 2456 + i);
#pragma unroll
    for (int r = 0; r < 4; ++r) {
      float2 x = *(const float2*)(xb + r * 576 + i);
      acc[r][0] = fmaf(w0.x, x.x, fmaf(w0.y, x.y, acc[r][0]));
      acc[r][1] = fmaf(w1.x, x.x, fmaf(w1.y, x.y, acc[r][1]));
      acc[r][2] = fmaf(w2.x, x.x, fmaf(w2.y, x.y, acc[r][2]));
    }
  }
  if (i < i1) {
    float w0 = wsm[i], w1 = wsm[1228 + i], w2 = wsm[2456 + i];
#pragma unroll
    for (int r = 0; r < 4; ++r) {
      float x = xb[r * 576 + i];
      acc[r][0] = fmaf(w0, x, acc[r][0]);
      acc[r][1] = fmaf(w1, x, acc[r][1]);
      acc[r][2] = fmaf(w2, x, acc[r][2]);
    }
  }
#pragma unroll
  for (int r = 0; r < 4; ++r)
#pragma unroll
    for (int ch = 0; ch < 3; ++ch)
      red[kc * 384 + s * 12 + r * 3 + ch] = acc[r][ch];
  __syncthreads();
  float v0 = cb[tid % 3];
#pragma unroll
  for (int c2 = 0; c2 < 8; ++c2) v0 += red[c2 * 384 + tid];
  pm2[tid] = v0;
  if (tid < 128) {
    float v1 = cb[(tid + 256) % 3];
#pragma unroll
    for (int c2 = 0; c2 < 8; ++c2) v1 += red[c2 * 384 + tid + 256];
    pm2[tid + 256] = v1;
  }
  __syncthreads();
  float st[6] = {0.f, 0.f, 0.f, 0.f, 0.f, 0.f};
  if (tid < 128 && tid < nvalid) {
    const int s2 = tid & 31, r2 = tid >> 5;
    float y0 = pm2[s2 * 12 + r2 * 3 + 0];
    float y1 = pm2[s2 * 12 + r2 * 3 + 1];
    float y2 = pm2[s2 * 12 + r2 * 3 + 2];
    float* op = out + b * 10203 + oh0 + tid;
    op[0] = y0; op[3401] = y1; op[6802] = y2;
    st[0] = y0; st[1] = y0 * y0; st[2] = y1; st[3] = y1 * y1; st[4] = y2; st[5] = y2 * y2;
  }
  const int lane = tid & 63, wid = tid >> 6;
#pragma unroll
  for (int c = 0; c < 6; ++c) {
    float rv = wred(st[c]);
    if (lane == 0) redm[wid][c] = rv;
  }
  __syncthreads();
  if (tid < 6)
    part[tid * 864 + blockIdx.x] = redm[0][tid] + redm[1][tid] + redm[2][tid] + redm[3][tid];
}

// ---------------- conv2: u-plane decomposition, fully aligned LDS reads ----------------
__global__ __launch_bounds__(256) void k_conv2(
    const float* __restrict__ x1, const float* __restrict__ part1,
    const float* __restrict__ g1, const float* __restrict__ be1,
    const float* __restrict__ cw, const float* __restrict__ cb,
    float* __restrict__ out, float* __restrict__ part) {
  __shared__ float wT[3024];      // [u][c][t] rows of 336, zero-padded t>=330
  __shared__ float P[3][852];     // input planes
  __shared__ float red[1536];     // kc1 partials: 128 slots x 12
  __shared__ float redm[4][6];
  __shared__ float coef[6];
  const int tid = threadIdx.x;
  const int lane = tid & 63, wid = tid >> 6;
  {  // reduce conv1 stats (transposed: part1[c*864 + blk]) -> bn1 coefficients
    float r6[6] = {0.f, 0.f, 0.f, 0.f, 0.f, 0.f};
    for (int j = tid; j < 864; j += 256) {
#pragma unroll
      for (int c = 0; c < 6; ++c) r6[c] += part1[c * 864 + j];
    }
#pragma unroll
    for (int c = 0; c < 6; ++c) {
      float rv = wred(r6[c]);
      if (lane == 0) redm[wid][c] = rv;
    }
    __syncthreads();
    if (tid == 0) {
      const float inv_n = 1.f / (32.f * 3401.f);
#pragma unroll
      for (int c = 0; c < 3; ++c) {
        float s = redm[0][2 * c] + redm[1][2 * c] + redm[2][2 * c] + redm[3][2 * c];
        float ss = redm[0][2 * c + 1] + redm[1][2 * c + 1] + redm[2][2 * c + 1] + redm[3][2 * c + 1];
        float m = s * inv_n;
        float var = ss * inv_n - m * m;
        float a = g1[c] * rsqrtf(var + EPSF);
        coef[c] = a; coef[3 + c] = be1[c] - m * a;
      }
    }
  }
  // stage transposed weights: wT[u*1008 + c*336 + t] = cw[c*990 + 3t + u], 0 for t>=330
  for (int j = tid; j < 3024; j += 256) {
    int u = j / 1008, rem = j - u * 1008;
    int c = rem / 336, t = rem - c * 336;
    wT[j] = (t < 330) ? cw[c * 990 + 3 * t + u] : 0.f;
  }
  __syncthreads();  // coef + wT ready
  const int tile = blockIdx.x % 6, b = blockIdx.x / 6;
  const int oh0 = tile << 9;
  const int zbase = oh0 * 3;
  const float* src = x1 + b * 10203 + zbase;
  // stage bn1-transformed planes (coalesced global reads)
  for (int j = tid; j < 2556; j += 256) {
    int rel = j / 3, u = j - rel * 3;
    float val = 0.f;
    int z = zbase + j;
    if (z <= 10202) {
      int c = (z >= 6802) ? 2 : ((z >= 3401) ? 1 : 0);
      val = fmaf(coef[c], src[j], coef[3 + c]);
    }
    P[u][rel] = val;
  }
  __syncthreads();
  const int kc = tid >> 7, s = tid & 127;
  const int t0 = kc * 168;
  const int xb = s << 2;
  float acc0[4] = {}, acc1[4] = {}, acc2[4] = {};
  float4 cur0 = *(const float4*)&P[0][xb + t0];
  float4 cur1 = *(const float4*)&P[1][xb + t0];
  float4 cur2 = *(const float4*)&P[2][xb + t0];
  float4 nxt0 = *(const float4*)&P[0][xb + t0 + 4];
  float4 nxt1 = *(const float4*)&P[1][xb + t0 + 4];
  float4 nxt2 = *(const float4*)&P[2][xb + t0 + 4];
  const int tend = t0 + 168;
  for (int tg = t0; tg < tend; tg += 4) {
#define CONV2_U(ACC0, ACC1, ACC2, UOFF, CUR, NXT)                                                  \
    {                                                                                              \
      const float* wu = wT + UOFF + tg;                                                            \
      float2 wa0 = *(const float2*)(wu);                                                           \
      float2 wb0 = *(const float2*)(wu + 2);                                                       \
      float2 wa1 = *(const float2*)(wu + 336);                                                     \
      float2 wb1 = *(const float2*)(wu + 338);                                                     \
      float2 wa2 = *(const float2*)(wu + 672);                                                     \
      float2 wb2 = *(const float2*)(wu + 674);                                                     \
      float x0 = CUR.x, x1v = CUR.y, x2v = CUR.z, x3v = CUR.w;                                     \
      float x4 = NXT.x, x5 = NXT.y, x6 = NXT.z;                                                    \
      ACC0[0] = fmaf(wa0.x, x0,  fmaf(wa0.y, x1v, fmaf(wb0.x, x2v, fmaf(wb0.y, x3v, ACC0[0]))));  \
      ACC0[1] = fmaf(wa0.x, x1v, fmaf(wa0.y, x2v, fmaf(wb0.x, x3v, fmaf(wb0.y, x4,  ACC0[1]))));  \
      ACC0[2] = fmaf(wa0.x, x2v, fmaf(wa0.y, x3v, fmaf(wb0.x, x4,  fmaf(wb0.y, x5,  ACC0[2]))));  \
      ACC0[3] = fmaf(wa0.x, x3v, fmaf(wa0.y, x4,  fmaf(wb0.x, x5,  fmaf(wb0.y, x6,  ACC0[3]))));  \
      ACC1[0] = fmaf(wa1.x, x0,  fmaf(wa1.y, x1v, fmaf(wb1.x, x2v, fmaf(wb1.y, x3v, ACC1[0]))));  \
      ACC1[1] = fmaf(wa1.x, x1v, fmaf(wa1.y, x2v, fmaf(wb1.x, x3v, fmaf(wb1.y, x4,  ACC1[1]))));  \
      ACC1[2] = fmaf(wa1.x, x2v, fmaf(wa1.y, x3v, fmaf(wb1.x, x4,  fmaf(wb1.y, x5,  ACC1[2]))));  \
      ACC1[3] = fmaf(wa1.x, x3v, fmaf(wa1.y, x4,  fmaf(wb1.x, x5,  fmaf(wb1.y, x6,  ACC1[3]))));  \
      ACC2[0] = fmaf(wa2.x, x0,  fmaf(wa2.y, x1v, fmaf(wb2.x, x2v, fmaf(wb2.y, x3v, ACC2[0]))));  \
      ACC2[1] = fmaf(wa2.x, x1v, fmaf(wa2.y, x2v, fmaf(wb2.x, x3v, fmaf(wb2.y, x4,  ACC2[1]))));  \
      ACC2[2] = fmaf(wa2.x, x2v, fmaf(wa2.y, x3v, fmaf(wb2.x, x4,  fmaf(wb2.y, x5,  ACC2[2]))));  \
      ACC2[3] = fmaf(wa2.x, x3v, fmaf(wa2.y, x4,  fmaf(wb2.x, x5,  fmaf(wb2.y, x6,  ACC2[3]))));  \
    }
    CONV2_U(acc0, acc1, acc2, 0,    cur0, nxt0)
    CONV2_U(acc0, acc1, acc2, 1008, cur1, nxt1)
    CONV2_U(acc0, acc1, acc2, 2016, cur2, nxt2)
#undef CONV2_U
    cur0 = nxt0; cur1 = nxt1; cur2 = nxt2;
    nxt0 = *(const float4*)&P[0][xb + tg + 8];
    nxt1 = *(const float4*)&P[1][xb + tg + 8];
    nxt2 = *(const float4*)&P[2][xb + tg + 8];
  }
  if (kc == 1) {
#pragma unroll
    for (int r = 0; r < 4; ++r) {
      red[s * 12 + r] = acc0[r];
      red[s * 12 + 4 + r] = acc1[r];
      red[s * 12 + 8 + r] = acc2[r];
    }
  }
  __syncthreads();
  float st[6] = {0.f, 0.f, 0.f, 0.f, 0.f, 0.f};
  if (kc == 0) {
    float y0[4], y1[4], y2[4];
#pragma unroll
    for (int r = 0; r < 4; ++r) {
      y0[r] = acc0[r] + red[s * 12 + r] + cb[0];
      y1[r] = acc1[r] + red[s * 12 + 4 + r] + cb[1];
      y2[r] = acc2[r] + red[s * 12 + 8 + r] + cb[2];
      st[0] += y0[r]; st[1] += y0[r] * y0[r];
      st[2] += y1[r]; st[3] += y1[r] * y1[r];
      st[4] += y2[r]; st[5] += y2[r] * y2[r];
    }
    float* op = out + b * 9216 + oh0 + xb;
    *(float4*)(op)        = make_float4(y0[0], y0[1], y0[2], y0[3]);
    *(float4*)(op + 3072) = make_float4(y1[0], y1[1], y1[2], y1[3]);
    *(float4*)(op + 6144) = make_float4(y2[0], y2[1], y2[2], y2[3]);
  }
#pragma unroll
  for (int c = 0; c < 6; ++c) {
    float rv = wred(st[c]);
    if (lane == 0) redm[wid][c] = rv;
  }
  __syncthreads();
  if (tid < 6)
    part[tid * 192 + blockIdx.x] = redm[0][tid] + redm[1][tid] + redm[2][tid] + redm[3][tid];
}

// ---------------- qkv: bn2 + prelu + 3x (9->4) ; q scaled by 1/sqrt(2)*log2(e) ----------------
__global__ __launch_bounds__(256) void k_qkv(
    const float* __restrict__ x2, const float* __restrict__ part2,
    const float* __restrict__ g2, const float* __restrict__ be2,
    const float* __restrict__ pa_p,
    const float* __restrict__ wq, const float* __restrict__ bq,
    const float* __restrict__ wk, const float* __restrict__ bk,
    const float* __restrict__ wv, const float* __restrict__ bv,
    float* __restrict__ qo, float* __restrict__ ko, float* __restrict__ vo) {
  __shared__ float redm[4][6];
  __shared__ float coef[6];
  const int tid = threadIdx.x;
  const int lane = tid & 63, wid = tid >> 6;
  {
    float r[6] = {0.f, 0.f, 0.f, 0.f, 0.f, 0.f};
    for (int j = tid; j < 192; j += 256) {
#pragma unroll
      for (int c = 0; c < 6; ++c) r[c] += part2[c * 192 + j];
    }
#pragma unroll
    for (int c = 0; c < 6; ++c) {
      float rv = wred(r[c]);
      if (lane == 0) redm[wid][c] = rv;
    }
    __syncthreads();
    if (tid == 0) {
      const float inv_n = 1.f / (32.f * 3072.f);
#pragma unroll
      for (int c = 0; c < 3; ++c) {
        float s = redm[0][2 * c] + redm[1][2 * c] + redm[2][2 * c] + redm[3][2 * c];
        float ss = redm[0][2 * c + 1] + redm[1][2 * c + 1] + redm[2][2 * c + 1] + redm[3][2 * c + 1];
        float m = s * inv_n;
        float var = ss * inv_n - m * m;
        float a = g2[c] * rsqrtf(var + EPSF);
        coef[c] = a; coef[3 + c] = be2[c] - m * a;
      }
    }
    __syncthreads();
  }
  const float pa = pa_p[0];
  const int id = blockIdx.x * 256 + tid;
  const int b = id >> 10, f = id & 1023;
  const float* src = x2 + b * 9216 + f * 9;
  float x[9];
  const int z0 = f * 9;
#pragma unroll
  for (int j = 0; j < 9; ++j) {
    int z = z0 + j;
    int c = (z >= 6144) ? 2 : ((z >= 3072) ? 1 : 0);
    float v = fmaf(coef[c], src[j], coef[3 + c]);
    x[j] = (v >= 0.f) ? v : pa * v;
  }
  const float QSCALE = 0.70710678118654752f * 1.44269504088896341f;  // 1/sqrt(HD) * log2(e)
#pragma unroll
  for (int dd = 0; dd < 4; ++dd) {
    float q = bq[dd], k = bk[dd], v = bv[dd];
#pragma unroll
    for (int j = 0; j < 9; ++j) {
      q = fmaf(wq[dd * 9 + j], x[j], q);
      k = fmaf(wk[dd * 9 + j], x[j], k);
      v = fmaf(wv[dd * 9 + j], x[j], v);
    }
    int hh = dd >> 1, d = dd & 1;
    int idx = ((b * 2 + hh) * 1024 + f) * 2 + d;
    qo[idx] = q * QSCALE;
    ko[idx] = k;
    vo[idx] = v;
  }
}

// ---------------- attention: per (b,h) softmax(qk)v, HD=2; bound-max single pass ----------------
__device__ __forceinline__ int kvIdx(int j) { return j + (j >> 7); }

__global__ __launch_bounds__(256) void k_attn(
    const float* __restrict__ q, const float* __restrict__ k,
    const float* __restrict__ v, float* __restrict__ av) {
  __shared__ float4 kv[1032];
  __shared__ float smax[4];
  const int tid = threadIdx.x;
  const int bh = blockIdx.x >> 3, rblk = blockIdx.x & 7;
  const float2* kp = (const float2*)(k + bh * 2048);
  const float2* vp = (const float2*)(v + bh * 2048);
  float nkm = 0.f;
  for (int j = tid; j < 1024; j += 256) {
    float2 kk = kp[j], vv = vp[j];
    kv[kvIdx(j)] = make_float4(kk.x, kk.y, vv.x, vv.y);
    nkm = fmaxf(nkm, fmaf(kk.x, kk.x, kk.y * kk.y));
  }
#pragma unroll
  for (int off = 32; off > 0; off >>= 1) nkm = fmaxf(nkm, __shfl_xor(nkm, off, 64));
  if ((tid & 63) == 0) smax[tid >> 6] = nkm;
  __syncthreads();
  const float knorm = sqrtf(fmaxf(fmaxf(smax[0], smax[1]), fmaxf(smax[2], smax[3])));
  const int lane = tid & 63, w = tid >> 6;
  const int rg = (w << 3) | (lane >> 3);
  const int ks = lane & 7;
  const int r0 = rblk * 128 + rg * 4;
  const float4 q01 = *(const float4*)(q + (bh * 1024 + r0) * 2);
  const float4 q23 = *(const float4*)(q + (bh * 1024 + r0) * 2 + 4);
  float qx[4] = {q01.x, q01.z, q23.x, q23.z};
  float qy[4] = {q01.y, q01.w, q23.y, q23.w};
  float m[4], l[4] = {0.f, 0.f, 0.f, 0.f};
  float o0[4] = {0.f, 0.f, 0.f, 0.f}, o1[4] = {0.f, 0.f, 0.f, 0.f};
#pragma unroll
  for (int r = 0; r < 4; ++r) m[r] = sqrtf(fmaf(qx[r], qx[r], qy[r] * qy[r])) * knorm;
  const int j0 = ks * 128;
#pragma unroll 4
  for (int jj = 0; jj < 128; ++jj) {
    float4 kk = kv[kvIdx(j0 + jj)];
#pragma unroll
    for (int r = 0; r < 4; ++r) {
      float s = fmaf(qx[r], kk.x, qy[r] * kk.y);
      float p = exp2f(s - m[r]);
      l[r] += p;
      o0[r] = fmaf(p, kk.z, o0[r]);
      o1[r] = fmaf(p, kk.w, o1[r]);
    }
  }
#pragma unroll
  for (int off = 1; off <= 4; off <<= 1) {
#pragma unroll
    for (int r = 0; r < 4; ++r) {
      l[r] += __shfl_xor(l[r], off, 64);
      o0[r] += __shfl_xor(o0[r], off, 64);
      o1[r] += __shfl_xor(o1[r], off, 64);
    }
  }
  if (ks == 0) {
    const int b = bh >> 1, hh = bh & 1;
#pragma unroll
    for (int r = 0; r < 4; ++r) {
      float rl = 1.f / l[r];
      *(float2*)(av + b * 4096 + (r0 + r) * 4 + hh * 2) = make_float2(o0[r] * rl, o1[r] * rl);
    }
  }
}

// ---------------- fc: [32,4096] x [1024,4096]^T, K-split partials ----------------
// grid 512 = 16 o-blocks(64) x 32 k-splits(128); thread = 4o x 2b
__global__ __launch_bounds__(256) void k_fc(
    const float* __restrict__ x, const float* __restrict__ w,
    float* __restrict__ pout) {
  __shared__ float xs[128 * 36];
  const int tid = threadIdx.x;
  const int ob = blockIdx.x & 15, ksp = blockIdx.x >> 4;
  const int k0 = ksp * 128, obase = ob * 64;
  for (int r = tid; r < 4096; r += 256) {
    int b = r >> 7, kk = r & 127;
    xs[kk * 36 + b] = x[b * 4096 + k0 + kk];
  }
  __syncthreads();
  const int og = tid & 15, bg = tid >> 4;
  const int o = obase + og * 4, bb0 = bg * 2;
  float acc[4][2] = {};
  const float* wp = w + o * 4096 + k0;
  for (int kk = 0; kk < 128; kk += 4) {
    float2 x0 = *(const float2*)&xs[(kk + 0) * 36 + bb0];
    float2 x1 = *(const float2*)&xs[(kk + 1) * 36 + bb0];
    float2 x2 = *(const float2*)&xs[(kk + 2) * 36 + bb0];
    float2 x3 = *(const float2*)&xs[(kk + 3) * 36 + bb0];
#pragma unroll
    for (int oo = 0; oo < 4; ++oo) {
      float4 wv = *(const float4*)(wp + oo * 4096 + kk);
      acc[oo][0] = fmaf(wv.x, x0.x, fmaf(wv.y, x1.x, fmaf(wv.z, x2.x, fmaf(wv.w, x3.x, acc[oo][0]))));
      acc[oo][1] = fmaf(wv.x, x0.y, fmaf(wv.y, x1.y, fmaf(wv.z, x2.y, fmaf(wv.w, x3.y, acc[oo][1]))));
    }
  }
#pragma unroll
  for (int bi = 0; bi < 2; ++bi) {
    float4 rv = make_float4(acc[0][bi], acc[1][bi], acc[2][bi], acc[3][bi]);
    *(float4*)&pout[(ksp * 32 + bb0 + bi) * 1024 + o] = rv;
  }
}

// ---------------- hred: h[b][o] = fc_b[o] + sum_j p_fc[j][b][o] ----------------
__global__ __launch_bounds__(256) void k_hred(
    const float* __restrict__ pfc, const float* __restrict__ fcb,
    float* __restrict__ h) {
  const int idx = blockIdx.x * 256 + threadIdx.x;
  const int b = idx >> 10, o = idx & 1023;
  float hv = fcb[o];
#pragma unroll 4
  for (int j = 0; j < 32; ++j) hv += pfc[(j * 32 + b) * 1024 + o];
  h[idx] = hv;
}

// ---------------- ff1: [32,1024] x [1024,1024]^T, reads h ----------------
// grid 256 = 16 o-blocks(64) x 16 k-splits(64)
__global__ __launch_bounds__(256) void k_ff1(
    const float* __restrict__ h, const float* __restrict__ w,
    float* __restrict__ pout) {
  __shared__ float xs[64 * 36];
  const int tid = threadIdx.x;
  const int ob = blockIdx.x & 15, ksp = blockIdx.x >> 4;
  const int k0 = ksp * 64, obase = ob * 64;
  for (int r = tid; r < 2048; r += 256) {
    int b = r >> 6, kk = r & 63;
    xs[kk * 36 + b] = h[b * 1024 + k0 + kk];
  }
  __syncthreads();
  const int og = tid & 15, bg = tid >> 4;
  const int o = obase + og * 4, bb0 = bg * 2;
  float acc[4][2] = {};
  const float* wp = w + o * 1024 + k0;
  for (int kk = 0; kk < 64; kk += 4) {
    float2 x0 = *(const float2*)&xs[(kk + 0) * 36 + bb0];
    float2 x1 = *(const float2*)&xs[(kk + 1) * 36 + bb0];
    float2 x2 = *(const float2*)&xs[(kk + 2) * 36 + bb0];
    float2 x3 = *(const float2*)&xs[(kk + 3) * 36 + bb0];
#pragma unroll
    for (int oo = 0; oo < 4; ++oo) {
      float4 wv = *(const float4*)(wp + oo * 1024 + kk);
      acc[oo][0] = fmaf(wv.x, x0.x, fmaf(wv.y, x1.x, fmaf(wv.z, x2.x, fmaf(wv.w, x3.x, acc[oo][0]))));
      acc[oo][1] = fmaf(wv.x, x0.y, fmaf(wv.y, x1.y, fmaf(wv.z, x2.y, fmaf(wv.w, x3.y, acc[oo][1]))));
    }
  }
#pragma unroll
  for (int bi = 0; bi < 2; ++bi) {
    float4 rv = make_float4(acc[0][bi], acc[1][bi], acc[2][bi], acc[3][bi]);
    *(float4*)&pout[(ksp * 32 + bb0 + bi) * 1024 + o] = rv;
  }
}

// ---------------- tail1 (per batch): LN+ELU+residual; ff2; gates; moe stage0 pre-bn ----------------
__global__ __launch_bounds__(256) void k_tail1(
    const float* __restrict__ h, const float* __restrict__ pff1,
    const float* __restrict__ ff1b,
    const float* __restrict__ lng, const float* __restrict__ lnb,
    const float* __restrict__ f2w, const float* __restrict__ f2b,
    const float* __restrict__ vp, const float* __restrict__ w0,
    const float* __restrict__ b0, float* __restrict__ wgate,
    float* __restrict__ s1pre) {
  __shared__ float hs[1024], ts[1024];
  __shared__ float mw_s[48];
  __shared__ float red2[4][2];
  __shared__ float bc[2];
  __shared__ float tot_s;
  const int b = blockIdx.x, tid = threadIdx.x;
  const int lane = tid & 63, wid = tid >> 6;
  for (int o = tid; o < 1024; o += 256) {
    hs[o] = h[b * 1024 + o];
    float tv = ff1b[o];
#pragma unroll 4
    for (int j = 0; j < 16; ++j) tv += pff1[(j * 32 + b) * 1024 + o];
    ts[o] = tv;
  }
  __syncthreads();
  float ls = 0.f, lss = 0.f;
  for (int o = tid; o < 1024; o += 256) {
    float t = ts[o];
    ls += t; lss += t * t;
  }
  ls = wred(ls); lss = wred(lss);
  if (lane == 0) { red2[wid][0] = ls; red2[wid][1] = lss; }
  __syncthreads();
  if (tid == 0) {
    float S = red2[0][0] + red2[1][0] + red2[2][0] + red2[3][0];
    float SS = red2[0][1] + red2[1][1] + red2[2][1] + red2[3][1];
    float m = S * (1.f / 1024.f);
    float var = SS * (1.f / 1024.f) - m * m;
    bc[0] = m; bc[1] = rsqrtf(var + EPSF);
  }
  __syncthreads();
  const float m = bc[0], inv = bc[1];
  for (int o = tid; o < 1024; o += 256) {
    float y = fmaf((ts[o] - m) * inv, lng[o], lnb[o]);
    float e = (y > 0.f) ? y : expm1f(y);
    ts[o] = hs[o] + e;  // h2
  }
  __syncthreads();
  if (tid < 192) {
    int e = tid >> 2, part = tid & 3;
    float acc = 0.f;
    const float* wr = f2w + e * 1024 + part * 4;
    for (int i = 0; i < 64; ++i) {
      float4 wv = *(const float4*)(wr + i * 16);
      int ob = i * 16 + part * 4;
      acc = fmaf(wv.x, ts[ob], fmaf(wv.y, ts[ob + 1], fmaf(wv.z, ts[ob + 2], fmaf(wv.w, ts[ob + 3], acc))));
    }
    acc += __shfl_down(acc, 1, 64);
    acc += __shfl_down(acc, 2, 64);
    if (part == 0) mw_s[e] = acc + f2b[e];
  }
  __syncthreads();
  if (tid < 64) {
    float v = (tid < 48) ? mw_s[tid] : 0.f;
    float t = wred(v);
    if (tid == 0) tot_s = t;
  }
  __syncthreads();
  if (tid < 48) {
    float wg = mw_s[tid] / tot_s;
    mw_s[tid] = wg;
    wgate[b * 48 + tid] = wg;
  }
  __syncthreads();
  if (tid < 32) {
    const int o = tid;
    const float v0 = vp[b * 3], v1 = vp[b * 3 + 1], v2 = vp[b * 3 + 2];
    float acc = 0.f;
#pragma unroll 4
    for (int e = 0; e < 48; ++e) {
      const float* wr = w0 + (e * 32 + o) * 3;
      float y = b0[e * 32 + o] + wr[0] * v0 + wr[1] * v1 + wr[2] * v2;
      acc = fmaf(mw_s[e], y, acc);
    }
    s1pre[b * 32 + o] = acc;
  }
}

// ---------------- moe1 (b x expert-chunk): bn over batch (redundant) + prelu + partial gated sum ----------------
// grid 256 = 32 b x 8 chunks of 6 experts; pmoe[ech][b][op] partials, reduced in k_final.
__global__ __launch_bounds__(128) void k_moe1(
    const float* __restrict__ s1pre, const float* __restrict__ g0,
    const float* __restrict__ be0, const float* __restrict__ pf_p,
    const float* __restrict__ wgate, const float* __restrict__ w1,
    const float* __restrict__ b1, float* __restrict__ pmoe) {
  __shared__ float s1n[32];
  __shared__ float wgs[6];
  const int tid = threadIdx.x;
  const int b = blockIdx.x >> 3, ech = blockIdx.x & 7;
  const int e0 = ech * 6;
  const float pf = pf_p[0];
  if (tid < 6) wgs[tid] = wgate[b * 48 + e0 + tid];
  if (tid < 32) {
    const int o = tid;
    float s = 0.f, ss = 0.f;
    for (int bb = 0; bb < 32; ++bb) {
      float v = s1pre[bb * 32 + o];
      s += v; ss += v * v;
    }
    float mm = s * (1.f / 32.f);
    float var = ss * (1.f / 32.f) - mm * mm;
    float a = g0[o] * rsqrtf(var + EPSF);
    float c = be0[o] - mm * a;
    float v = fmaf(s1pre[b * 32 + o], a, c);
    s1n[o] = (v >= 0.f) ? v : pf * v;
  }
  __syncthreads();
  const int op = tid;  // 0..127
  float acc = 0.f;
#pragma unroll
  for (int ee = 0; ee < 6; ++ee) {
    const int e = e0 + ee;
    const float* wr = w1 + (e * 128 + op) * 32;
    float y = b1[e * 128 + op];
#pragma unroll
    for (int i = 0; i < 32; i += 4) {
      float4 wv = *(const float4*)(wr + i);
      y = fmaf(wv.x, s1n[i], fmaf(wv.y, s1n[i + 1], fmaf(wv.z, s1n[i + 2], fmaf(wv.w, s1n[i + 3], y))));
    }
    acc = fmaf(wgs[ee], y, acc);
  }
  pmoe[ech * 4096 + b * 128 + op] = acc;
}

// ---------------- final: reduce 8 moe partials; bn over batch + prelu + dot(128) + sigmoid ----------------
__global__ __launch_bounds__(256) void k_final(
    const float* __restrict__ pmoe, const float* __restrict__ g1,
    const float* __restrict__ be1, const float* __restrict__ pf_p,
    const float* __restrict__ ow, const float* __restrict__ obp,
    float* __restrict__ outp) {
  __shared__ float s2[32 * 132];
  __shared__ float ca[128], cb[128];
  const int tid = threadIdx.x;
  for (int r = tid; r < 4096; r += 256) {
    int b = r >> 7, o = r & 127;
    float v = 0.f;
#pragma unroll
    for (int j = 0; j < 8; ++j) v += pmoe[j * 4096 + r];
    s2[b * 132 + o] = v;
  }
  __syncthreads();
  if (tid < 128) {
    const int o = tid;
    float s = 0.f, ss = 0.f;
    for (int b = 0; b < 32; ++b) {
      float v = s2[b * 132 + o];
      s += v; ss += v * v;
    }
    float mm = s * (1.f / 32.f);
    float var = ss * (1.f / 32.f) - mm * mm;
    float a = g1[o] * rsqrtf(var + EPSF);
    ca[o] = a; cb[o] = be1[o] - mm * a;
  }
  __syncthreads();
  const float pf = pf_p[0];
  if (tid < 32) {
    const int b = tid;
    float acc = 0.f;
#pragma unroll 4
    for (int o = 0; o < 128; ++o) {
      float v = fmaf(s2[b * 132 + o], ca[o], cb[o]);
      v = (v >= 0.f) ? v : pf * v;
      acc = fmaf(v, ow[o], acc);
    }
    float z = acc + obp[0];
    outp[b] = 1.f / (1.f + __expf(-z));
  }
}

// ---------------- launch ----------------
extern "C" void kernel_launch(void* const* d_in, const int* in_sizes, int n_in,
                              void* d_out, int out_size, void* d_ws, size_t ws_size,
                              hipStream_t stream) {
  (void)in_sizes; (void)n_in; (void)out_size; (void)ws_size;
  const float* vertex_pos = (const float*)d_in[0];
  const float* body_mesh  = (const float*)d_in[1];
  const float* conv1_w    = (const float*)d_in[2];
  const float* conv1_b    = (const float*)d_in[3];
  const float* bn1_g      = (const float*)d_in[4];
  const float* bn1_b      = (const float*)d_in[5];
  const float* conv2_w    = (const float*)d_in[6];
  const float* conv2_b    = (const float*)d_in[7];
  const float* bn2_g      = (const float*)d_in[8];
  const float* bn2_b      = (const float*)d_in[9];
  const float* prelu_a    = (const float*)d_in[10];
  const float* wq = (const float*)d_in[11]; const float* bq = (const float*)d_in[12];
  const float* wk = (const float*)d_in[13]; const float* bk = (const float*)d_in[14];
  const float* wv = (const float*)d_in[15]; const float* bv = (const float*)d_in[16];
  const float* fc_w  = (const float*)d_in[17]; const float* fc_b  = (const float*)d_in[18];
  const float* ff1_w = (const float*)d_in[19]; const float* ff1_b = (const float*)d_in[20];
  const float* ln_g  = (const float*)d_in[21]; const float* ln_b  = (const float*)d_in[22];
  const float* ff2_w = (const float*)d_in[23]; const float* ff2_b = (const float*)d_in[24];
  const float* fus_w0 = (const float*)d_in[25]; const float* fus_b0 = (const float*)d_in[26];
  const float* fus_w1 = (const float*)d_in[27]; const float* fus_b1 = (const float*)d_in[28];
  const float* bnf0_g = (const float*)d_in[29]; const float* bnf0_b = (const float*)d_in[30];
  const float* bnf1_g = (const float*)d_in[31]; const float* bnf1_b = (const float*)d_in[32];
  const float* prelu_f = (const float*)d_in[33];
  const float* out_w = (const float*)d_in[34]; const float* out_b = (const float*)d_in[35];

  float* ws = (float*)d_ws;
  float* conv1_out = ws + 0;        // 326496
  float* conv2_out = ws + 326496;   // -> 621408
  float* qws = ws + 621408;         // -> 752480
  float* kws = ws + 752480;         // -> 883552
  float* vws = ws + 883552;         // -> 1014624
  float* p_fc = ws + 0;             // 1048576 (overlays region A; dead by k_fc)
  float* av    = ws + 1048576;      // -> 1179648
  float* hbuf  = ws + 1179648;      // -> 1212416
  float* p_ff1 = ws + 1212416;      // -> 1736704
  float* part1 = ws + 1736704;      // 6*864 -> 1741888
  float* part2 = ws + 1741888;      // 6*192 -> 1746496
  float* wgate = ws + 1746496;      // -> 1748032
  float* s1pre = ws + 1748032;      // -> 1749056
  float* pmoe  = ws + 1749056;      // 8*4096 -> 1781824 floats (~7.1 MB)

  k_conv1<<<864, 256, 0, stream>>>(body_mesh, conv1_w, conv1_b, conv1_out, part1);
  k_conv2<<<192, 256, 0, stream>>>(conv1_out, part1, bn1_g, bn1_b, conv2_w, conv2_b, conv2_out, part2);
  k_qkv<<<128, 256, 0, stream>>>(conv2_out, part2, bn2_g, bn2_b, prelu_a,
                                 wq, bq, wk, bk, wv, bv, qws, kws, vws);
  k_attn<<<512, 256, 0, stream>>>(qws, kws, vws, av);
  k_fc<<<512, 256, 0, stream>>>(av, fc_w, p_fc);
  k_hred<<<128, 256, 0, stream>>>(p_fc, fc_b, hbuf);
  k_ff1<<<256, 256, 0, stream>>>(hbuf, ff1_w, p_ff1);
  k_tail1<<<32, 256, 0, stream>>>(hbuf, p_ff1, ff1_b, ln_g, ln_b, ff2_w, ff2_b,
                                  vertex_pos, fus_w0, fus_b0, wgate, s1pre);
  k_moe1<<<256, 128, 0, stream>>>(s1pre, bnf0_g, bnf0_b, prelu_f, wgate, fus_w1, fus_b1, pmoe);
  k_final<<<1, 256, 0, stream>>>(pmoe, bnf1_g, bnf1_b, prelu_f, out_w, out_b, (float*)d_out);
}

// Round 8
// 323.837 us; speedup vs baseline: 1.2933x; 1.0036x over previous
//
#include <hip/hip_runtime.h>

#define EPSF 1e-5f

// ---------------- helpers ----------------
__device__ __forceinline__ float wred(float v) {
#pragma unroll
  for (int off = 32; off > 0; off >>= 1) v += __shfl_down(v, off, 64);
  return v;
}

// ---------------- conv1: u-plane decomposition (i = 18t+u), fully aligned LDS reads ----------------
// out[c][oh] = cb[c] + sum_u sum_t wT[c][u][t] * P_u[oh+t],  P_u[p] = mesh[(oh0+p)*18+u].
// 128 outputs/block (32 slots x 4 consecutive); 8 u-chunks: {kc, kc+8, kc+16 if <18}.
__global__ __launch_bounds__(256) void k_conv1(
    const float* __restrict__ mesh, const float* __restrict__ cw,
    const float* __restrict__ cb, float* __restrict__ out,
    float* __restrict__ part) {
  __shared__ float wT[3888];    // (c*18+u)*72 + t, zero-padded t>=valid
  __shared__ float P[3672];     // 18 planes x 204
  __shared__ float red[3072];   // 8 chunks x 384 combos
  __shared__ float pm2[384];
  __shared__ float redm[4][6];
  const int tid = threadIdx.x;
  const int tile = blockIdx.x % 27, b = blockIdx.x / 27;
  const int oh0 = tile << 7;
  const int nvalid = min(128, 3401 - oh0);
  // stage transposed weights: wT[(c*18+u)*72+t] = cw[c*1227 + 18t+u], 0 when 18t+u >= 1227
  for (int j = tid; j < 3888; j += 256) {
    int c = j / 1296, rem = j - c * 1296;
    int u = rem / 72, t = rem - u * 72;
    int i = 18 * t + u;
    wT[j] = (i < 1227) ? cw[c * 1227 + i] : 0.f;
  }
  // stage planes (coalesced: consecutive j -> consecutive global z)
  {
    const int zoff = oh0 * 18;
    const float* src = mesh + b * 62439;
    for (int j = tid; j < 3672; j += 256) {
      int p = j / 18, u = j - p * 18;
      int z = zoff + j;
      P[u * 204 + p] = (z < 62439) ? src[z] : 0.f;
    }
  }
  __syncthreads();
  const int kc = tid >> 5, s = tid & 31;
  const int xb = s << 2;
  const int nu = (kc < 2) ? 3 : 2;
  float acc[3][4] = {};
  for (int ui = 0; ui < nu; ++ui) {
    const int u = (ui == 0) ? kc : ((ui == 1) ? kc + 8 : kc + 16);
    const float* Pu = P + u * 204 + xb;
    const float* w0p = wT + u * 72;
    const float* w1p = wT + 1296 + u * 72;
    const float* w2p = wT + 2592 + u * 72;
    float4 cur = *(const float4*)(Pu);
    float4 nxt = *(const float4*)(Pu + 4);
#pragma unroll 6
    for (int tg = 0; tg < 72; tg += 4) {
      float4 wv0 = *(const float4*)(w0p + tg);
      float4 wv1 = *(const float4*)(w1p + tg);
      float4 wv2 = *(const float4*)(w2p + tg);
      float x0 = cur.x, x1 = cur.y, x2 = cur.z, x3 = cur.w;
      float x4 = nxt.x, x5 = nxt.y, x6 = nxt.z;
      acc[0][0] = fmaf(wv0.x, x0, fmaf(wv0.y, x1, fmaf(wv0.z, x2, fmaf(wv0.w, x3, acc[0][0]))));
      acc[0][1] = fmaf(wv0.x, x1, fmaf(wv0.y, x2, fmaf(wv0.z, x3, fmaf(wv0.w, x4, acc[0][1]))));
      acc[0][2] = fmaf(wv0.x, x2, fmaf(wv0.y, x3, fmaf(wv0.z, x4, fmaf(wv0.w, x5, acc[0][2]))));
      acc[0][3] = fmaf(wv0.x, x3, fmaf(wv0.y, x4, fmaf(wv0.z, x5, fmaf(wv0.w, x6, acc[0][3]))));
      acc[1][0] = fmaf(wv1.x, x0, fmaf(wv1.y, x1, fmaf(wv1.z, x2, fmaf(wv1.w, x3, acc[1][0]))));
      acc[1][1] = fmaf(wv1.x, x1, fmaf(wv1.y, x2, fmaf(wv1.z, x3, fmaf(wv1.w, x4, acc[1][1]))));
      acc[1][2] = fmaf(wv1.x, x2, fmaf(wv1.y, x3, fmaf(wv1.z, x4, fmaf(wv1.w, x5, acc[1][2]))));
      acc[1][3] = fmaf(wv1.x, x3, fmaf(wv1.y, x4, fmaf(wv1.z, x5, fmaf(wv1.w, x6, acc[1][3]))));
      acc[2][0] = fmaf(wv2.x, x0, fmaf(wv2.y, x1, fmaf(wv2.z, x2, fmaf(wv2.w, x3, acc[2][0]))));
      acc[2][1] = fmaf(wv2.x, x1, fmaf(wv2.y, x2, fmaf(wv2.z, x3, fmaf(wv2.w, x4, acc[2][1]))));
      acc[2][2] = fmaf(wv2.x, x2, fmaf(wv2.y, x3, fmaf(wv2.z, x4, fmaf(wv2.w, x5, acc[2][2]))));
      acc[2][3] = fmaf(wv2.x, x3, fmaf(wv2.y, x4, fmaf(wv2.z, x5, fmaf(wv2.w, x6, acc[2][3]))));
      cur = nxt;
      nxt = *(const float4*)(Pu + tg + 8);
    }
  }
#pragma unroll
  for (int r = 0; r < 4; ++r)
#pragma unroll
    for (int ch = 0; ch < 3; ++ch)
      red[kc * 384 + s * 12 + r * 3 + ch] = acc[ch][r];
  __syncthreads();
  float v0 = cb[tid % 3];
#pragma unroll
  for (int c2 = 0; c2 < 8; ++c2) v0 += red[c2 * 384 + tid];
  pm2[tid] = v0;
  if (tid < 128) {
    float v1 = cb[(tid + 256) % 3];
#pragma unroll
    for (int c2 = 0; c2 < 8; ++c2) v1 += red[c2 * 384 + tid + 256];
    pm2[tid + 256] = v1;
  }
  __syncthreads();
  float st[6] = {0.f, 0.f, 0.f, 0.f, 0.f, 0.f};
  if (tid < nvalid) {
    const int s2 = tid >> 2, r2 = tid & 3;
    float y0 = pm2[s2 * 12 + r2 * 3 + 0];
    float y1 = pm2[s2 * 12 + r2 * 3 + 1];
    float y2 = pm2[s2 * 12 + r2 * 3 + 2];
    float* op = out + b * 10203 + oh0 + tid;
    op[0] = y0; op[3401] = y1; op[6802] = y2;
    st[0] = y0; st[1] = y0 * y0; st[2] = y1; st[3] = y1 * y1; st[4] = y2; st[5] = y2 * y2;
  }
  const int lane = tid & 63, wid = tid >> 6;
#pragma unroll
  for (int c = 0; c < 6; ++c) {
    float rv = wred(st[c]);
    if (lane == 0) redm[wid][c] = rv;
  }
  __syncthreads();
  if (tid < 6)
    part[tid * 864 + blockIdx.x] = redm[0][tid] + redm[1][tid] + redm[2][tid] + redm[3][tid];
}

// ---------------- conv2: u-plane decomposition, fully aligned LDS reads ----------------
__global__ __launch_bounds__(256) void k_conv2(
    const float* __restrict__ x1, const float* __restrict__ part1,
    const float* __restrict__ g1, const float* __restrict__ be1,
    const float* __restrict__ cw, const float* __restrict__ cb,
    float* __restrict__ out, float* __restrict__ part) {
  __shared__ float wT[3024];      // [u][c][t] rows of 336, zero-padded t>=330
  __shared__ float P[3][852];     // input planes
  __shared__ float red[1536];     // kc1 partials: 128 slots x 12
  __shared__ float redm[4][6];
  __shared__ float coef[6];
  const int tid = threadIdx.x;
  const int lane = tid & 63, wid = tid >> 6;
  {  // reduce conv1 stats (transposed: part1[c*864 + blk]) -> bn1 coefficients
    float r6[6] = {0.f, 0.f, 0.f, 0.f, 0.f, 0.f};
    for (int j = tid; j < 864; j += 256) {
#pragma unroll
      for (int c = 0; c < 6; ++c) r6[c] += part1[c * 864 + j];
    }
#pragma unroll
    for (int c = 0; c < 6; ++c) {
      float rv = wred(r6[c]);
      if (lane == 0) redm[wid][c] = rv;
    }
    __syncthreads();
    if (tid == 0) {
      const float inv_n = 1.f / (32.f * 3401.f);
#pragma unroll
      for (int c = 0; c < 3; ++c) {
        float s = redm[0][2 * c] + redm[1][2 * c] + redm[2][2 * c] + redm[3][2 * c];
        float ss = redm[0][2 * c + 1] + redm[1][2 * c + 1] + redm[2][2 * c + 1] + redm[3][2 * c + 1];
        float m = s * inv_n;
        float var = ss * inv_n - m * m;
        float a = g1[c] * rsqrtf(var + EPSF);
        coef[c] = a; coef[3 + c] = be1[c] - m * a;
      }
    }
  }
  // stage transposed weights: wT[u*1008 + c*336 + t] = cw[c*990 + 3t + u], 0 for t>=330
  for (int j = tid; j < 3024; j += 256) {
    int u = j / 1008, rem = j - u * 1008;
    int c = rem / 336, t = rem - c * 336;
    wT[j] = (t < 330) ? cw[c * 990 + 3 * t + u] : 0.f;
  }
  __syncthreads();  // coef + wT ready
  const int tile = blockIdx.x % 6, b = blockIdx.x / 6;
  const int oh0 = tile << 9;
  const int zbase = oh0 * 3;
  const float* src = x1 + b * 10203 + zbase;
  // stage bn1-transformed planes (coalesced global reads)
  for (int j = tid; j < 2556; j += 256) {
    int rel = j / 3, u = j - rel * 3;
    float val = 0.f;
    int z = zbase + j;
    if (z <= 10202) {
      int c = (z >= 6802) ? 2 : ((z >= 3401) ? 1 : 0);
      val = fmaf(coef[c], src[j], coef[3 + c]);
    }
    P[u][rel] = val;
  }
  __syncthreads();
  const int kc = tid >> 7, s = tid & 127;
  const int t0 = kc * 168;
  const int xb = s << 2;
  float acc0[4] = {}, acc1[4] = {}, acc2[4] = {};
  float4 cur0 = *(const float4*)&P[0][xb + t0];
  float4 cur1 = *(const float4*)&P[1][xb + t0];
  float4 cur2 = *(const float4*)&P[2][xb + t0];
  float4 nxt0 = *(const float4*)&P[0][xb + t0 + 4];
  float4 nxt1 = *(const float4*)&P[1][xb + t0 + 4];
  float4 nxt2 = *(const float4*)&P[2][xb + t0 + 4];
  const int tend = t0 + 168;
  for (int tg = t0; tg < tend; tg += 4) {
#define CONV2_U(ACC0, ACC1, ACC2, UOFF, CUR, NXT)                                                  \
    {                                                                                              \
      const float* wu = wT + UOFF + tg;                                                            \
      float2 wa0 = *(const float2*)(wu);                                                           \
      float2 wb0 = *(const float2*)(wu + 2);                                                       \
      float2 wa1 = *(const float2*)(wu + 336);                                                     \
      float2 wb1 = *(const float2*)(wu + 338);                                                     \
      float2 wa2 = *(const float2*)(wu + 672);                                                     \
      float2 wb2 = *(const float2*)(wu + 674);                                                     \
      float x0 = CUR.x, x1v = CUR.y, x2v = CUR.z, x3v = CUR.w;                                     \
      float x4 = NXT.x, x5 = NXT.y, x6 = NXT.z;                                                    \
      ACC0[0] = fmaf(wa0.x, x0,  fmaf(wa0.y, x1v, fmaf(wb0.x, x2v, fmaf(wb0.y, x3v, ACC0[0]))));  \
      ACC0[1] = fmaf(wa0.x, x1v, fmaf(wa0.y, x2v, fmaf(wb0.x, x3v, fmaf(wb0.y, x4,  ACC0[1]))));  \
      ACC0[2] = fmaf(wa0.x, x2v, fmaf(wa0.y, x3v, fmaf(wb0.x, x4,  fmaf(wb0.y, x5,  ACC0[2]))));  \
      ACC0[3] = fmaf(wa0.x, x3v, fmaf(wa0.y, x4,  fmaf(wb0.x, x5,  fmaf(wb0.y, x6,  ACC0[3]))));  \
      ACC1[0] = fmaf(wa1.x, x0,  fmaf(wa1.y, x1v, fmaf(wb1.x, x2v, fmaf(wb1.y, x3v, ACC1[0]))));  \
      ACC1[1] = fmaf(wa1.x, x1v, fmaf(wa1.y, x2v, fmaf(wb1.x, x3v, fmaf(wb1.y, x4,  ACC1[1]))));  \
      ACC1[2] = fmaf(wa1.x, x2v, fmaf(wa1.y, x3v, fmaf(wb1.x, x4,  fmaf(wb1.y, x5,  ACC1[2]))));  \
      ACC1[3] = fmaf(wa1.x, x3v, fmaf(wa1.y, x4,  fmaf(wb1.x, x5,  fmaf(wb1.y, x6,  ACC1[3]))));  \
      ACC2[0] = fmaf(wa2.x, x0,  fmaf(wa2.y, x1v, fmaf(wb2.x, x2v, fmaf(wb2.y, x3v, ACC2[0]))));  \
      ACC2[1] = fmaf(wa2.x, x1v, fmaf(wa2.y, x2v, fmaf(wb2.x, x3v, fmaf(wb2.y, x4,  ACC2[1]))));  \
      ACC2[2] = fmaf(wa2.x, x2v, fmaf(wa2.y, x3v, fmaf(wb2.x, x4,  fmaf(wb2.y, x5,  ACC2[2]))));  \
      ACC2[3] = fmaf(wa2.x, x3v, fmaf(wa2.y, x4,  fmaf(wb2.x, x5,  fmaf(wb2.y, x6,  ACC2[3]))));  \
    }
    CONV2_U(acc0, acc1, acc2, 0,    cur0, nxt0)
    CONV2_U(acc0, acc1, acc2, 1008, cur1, nxt1)
    CONV2_U(acc0, acc1, acc2, 2016, cur2, nxt2)
#undef CONV2_U
    cur0 = nxt0; cur1 = nxt1; cur2 = nxt2;
    nxt0 = *(const float4*)&P[0][xb + tg + 8];
    nxt1 = *(const float4*)&P[1][xb + tg + 8];
    nxt2 = *(const float4*)&P[2][xb + tg + 8];
  }
  if (kc == 1) {
#pragma unroll
    for (int r = 0; r < 4; ++r) {
      red[s * 12 + r] = acc0[r];
      red[s * 12 + 4 + r] = acc1[r];
      red[s * 12 + 8 + r] = acc2[r];
    }
  }
  __syncthreads();
  float st[6] = {0.f, 0.f, 0.f, 0.f, 0.f, 0.f};
  if (kc == 0) {
    float y0[4], y1[4], y2[4];
#pragma unroll
    for (int r = 0; r < 4; ++r) {
      y0[r] = acc0[r] + red[s * 12 + r] + cb[0];
      y1[r] = acc1[r] + red[s * 12 + 4 + r] + cb[1];
      y2[r] = acc2[r] + red[s * 12 + 8 + r] + cb[2];
      st[0] += y0[r]; st[1] += y0[r] * y0[r];
      st[2] += y1[r]; st[3] += y1[r] * y1[r];
      st[4] += y2[r]; st[5] += y2[r] * y2[r];
    }
    float* op = out + b * 9216 + oh0 + xb;
    *(float4*)(op)        = make_float4(y0[0], y0[1], y0[2], y0[3]);
    *(float4*)(op + 3072) = make_float4(y1[0], y1[1], y1[2], y1[3]);
    *(float4*)(op + 6144) = make_float4(y2[0], y2[1], y2[2], y2[3]);
  }
#pragma unroll
  for (int c = 0; c < 6; ++c) {
    float rv = wred(st[c]);
    if (lane == 0) redm[wid][c] = rv;
  }
  __syncthreads();
  if (tid < 6)
    part[tid * 192 + blockIdx.x] = redm[0][tid] + redm[1][tid] + redm[2][tid] + redm[3][tid];
}

// ---------------- qkv: bn2 + prelu + 3x (9->4) ; q scaled by 1/sqrt(2)*log2(e) ----------------
__global__ __launch_bounds__(256) void k_qkv(
    const float* __restrict__ x2, const float* __restrict__ part2,
    const float* __restrict__ g2, const float* __restrict__ be2,
    const float* __restrict__ pa_p,
    const float* __restrict__ wq, const float* __restrict__ bq,
    const float* __restrict__ wk, const float* __restrict__ bk,
    const float* __restrict__ wv, const float* __restrict__ bv,
    float* __restrict__ qo, float* __restrict__ ko, float* __restrict__ vo) {
  __shared__ float redm[4][6];
  __shared__ float coef[6];
  const int tid = threadIdx.x;
  const int lane = tid & 63, wid = tid >> 6;
  {
    float r[6] = {0.f, 0.f, 0.f, 0.f, 0.f, 0.f};
    for (int j = tid; j < 192; j += 256) {
#pragma unroll
      for (int c = 0; c < 6; ++c) r[c] += part2[c * 192 + j];
    }
#pragma unroll
    for (int c = 0; c < 6; ++c) {
      float rv = wred(r[c]);
      if (lane == 0) redm[wid][c] = rv;
    }
    __syncthreads();
    if (tid == 0) {
      const float inv_n = 1.f / (32.f * 3072.f);
#pragma unroll
      for (int c = 0; c < 3; ++c) {
        float s = redm[0][2 * c] + redm[1][2 * c] + redm[2][2 * c] + redm[3][2 * c];
        float ss = redm[0][2 * c + 1] + redm[1][2 * c + 1] + redm[2][2 * c + 1] + redm[3][2 * c + 1];
        float m = s * inv_n;
        float var = ss * inv_n - m * m;
        float a = g2[c] * rsqrtf(var + EPSF);
        coef[c] = a; coef[3 + c] = be2[c] - m * a;
      }
    }
    __syncthreads();
  }
  const float pa = pa_p[0];
  const int id = blockIdx.x * 256 + tid;
  const int b = id >> 10, f = id & 1023;
  const float* src = x2 + b * 9216 + f * 9;
  float x[9];
  const int z0 = f * 9;
#pragma unroll
  for (int j = 0; j < 9; ++j) {
    int z = z0 + j;
    int c = (z >= 6144) ? 2 : ((z >= 3072) ? 1 : 0);
    float v = fmaf(coef[c], src[j], coef[3 + c]);
    x[j] = (v >= 0.f) ? v : pa * v;
  }
  const float QSCALE = 0.70710678118654752f * 1.44269504088896341f;  // 1/sqrt(HD) * log2(e)
#pragma unroll
  for (int dd = 0; dd < 4; ++dd) {
    float q = bq[dd], k = bk[dd], v = bv[dd];
#pragma unroll
    for (int j = 0; j < 9; ++j) {
      q = fmaf(wq[dd * 9 + j], x[j], q);
      k = fmaf(wk[dd * 9 + j], x[j], k);
      v = fmaf(wv[dd * 9 + j], x[j], v);
    }
    int hh = dd >> 1, d = dd & 1;
    int idx = ((b * 2 + hh) * 1024 + f) * 2 + d;
    qo[idx] = q * QSCALE;
    ko[idx] = k;
    vo[idx] = v;
  }
}

// ---------------- attention: per (b,h) softmax(qk)v, HD=2; bound-max single pass ----------------
__device__ __forceinline__ int kvIdx(int j) { return j + (j >> 7); }

__global__ __launch_bounds__(256) void k_attn(
    const float* __restrict__ q, const float* __restrict__ k,
    const float* __restrict__ v, float* __restrict__ av) {
  __shared__ float4 kv[1032];
  __shared__ float smax[4];
  const int tid = threadIdx.x;
  const int bh = blockIdx.x >> 3, rblk = blockIdx.x & 7;
  const float2* kp = (const float2*)(k + bh * 2048);
  const float2* vp = (const float2*)(v + bh * 2048);
  float nkm = 0.f;
  for (int j = tid; j < 1024; j += 256) {
    float2 kk = kp[j], vv = vp[j];
    kv[kvIdx(j)] = make_float4(kk.x, kk.y, vv.x, vv.y);
    nkm = fmaxf(nkm, fmaf(kk.x, kk.x, kk.y * kk.y));
  }
#pragma unroll
  for (int off = 32; off > 0; off >>= 1) nkm = fmaxf(nkm, __shfl_xor(nkm, off, 64));
  if ((tid & 63) == 0) smax[tid >> 6] = nkm;
  __syncthreads();
  const float knorm = sqrtf(fmaxf(fmaxf(smax[0], smax[1]), fmaxf(smax[2], smax[3])));
  const int lane = tid & 63, w = tid >> 6;
  const int rg = (w << 3) | (lane >> 3);
  const int ks = lane & 7;
  const int r0 = rblk * 128 + rg * 4;
  const float4 q01 = *(const float4*)(q + (bh * 1024 + r0) * 2);
  const float4 q23 = *(const float4*)(q + (bh * 1024 + r0) * 2 + 4);
  float qx[4] = {q01.x, q01.z, q23.x, q23.z};
  float qy[4] = {q01.y, q01.w, q23.y, q23.w};
  float m[4], l[4] = {0.f, 0.f, 0.f, 0.f};
  float o0[4] = {0.f, 0.f, 0.f, 0.f}, o1[4] = {0.f, 0.f, 0.f, 0.f};
#pragma unroll
  for (int r = 0; r < 4; ++r) m[r] = sqrtf(fmaf(qx[r], qx[r], qy[r] * qy[r])) * knorm;
  const int j0 = ks * 128;
#pragma unroll 4
  for (int jj = 0; jj < 128; ++jj) {
    float4 kk = kv[kvIdx(j0 + jj)];
#pragma unroll
    for (int r = 0; r < 4; ++r) {
      float s = fmaf(qx[r], kk.x, qy[r] * kk.y);
      float p = exp2f(s - m[r]);
      l[r] += p;
      o0[r] = fmaf(p, kk.z, o0[r]);
      o1[r] = fmaf(p, kk.w, o1[r]);
    }
  }
#pragma unroll
  for (int off = 1; off <= 4; off <<= 1) {
#pragma unroll
    for (int r = 0; r < 4; ++r) {
      l[r] += __shfl_xor(l[r], off, 64);
      o0[r] += __shfl_xor(o0[r], off, 64);
      o1[r] += __shfl_xor(o1[r], off, 64);
    }
  }
  if (ks == 0) {
    const int b = bh >> 1, hh = bh & 1;
#pragma unroll
    for (int r = 0; r < 4; ++r) {
      float rl = 1.f / l[r];
      *(float2*)(av + b * 4096 + (r0 + r) * 4 + hh * 2) = make_float2(o0[r] * rl, o1[r] * rl);
    }
  }
}

// ---------------- fc: [32,4096] x [1024,4096]^T, K-split partials ----------------
// grid 512 = 16 o-blocks(64) x 32 k-splits(128); thread = 4o x 2b
__global__ __launch_bounds__(256) void k_fc(
    const float* __restrict__ x, const float* __restrict__ w,
    float* __restrict__ pout) {
  __shared__ float xs[128 * 36];
  const int tid = threadIdx.x;
  const int ob = blockIdx.x & 15, ksp = blockIdx.x >> 4;
  const int k0 = ksp * 128, obase = ob * 64;
  for (int r = tid; r < 4096; r += 256) {
    int b = r >> 7, kk = r & 127;
    xs[kk * 36 + b] = x[b * 4096 + k0 + kk];
  }
  __syncthreads();
  const int og = tid & 15, bg = tid >> 4;
  const int o = obase + og * 4, bb0 = bg * 2;
  float acc[4][2] = {};
  const float* wp = w + o * 4096 + k0;
  for (int kk = 0; kk < 128; kk += 4) {
    float2 x0 = *(const float2*)&xs[(kk + 0) * 36 + bb0];
    float2 x1 = *(const float2*)&xs[(kk + 1) * 36 + bb0];
    float2 x2 = *(const float2*)&xs[(kk + 2) * 36 + bb0];
    float2 x3 = *(const float2*)&xs[(kk + 3) * 36 + bb0];
#pragma unroll
    for (int oo = 0; oo < 4; ++oo) {
      float4 wv = *(const float4*)(wp + oo * 4096 + kk);
      acc[oo][0] = fmaf(wv.x, x0.x, fmaf(wv.y, x1.x, fmaf(wv.z, x2.x, fmaf(wv.w, x3.x, acc[oo][0]))));
      acc[oo][1] = fmaf(wv.x, x0.y, fmaf(wv.y, x1.y, fmaf(wv.z, x2.y, fmaf(wv.w, x3.y, acc[oo][1]))));
    }
  }
#pragma unroll
  for (int bi = 0; bi < 2; ++bi) {
    float4 rv = make_float4(acc[0][bi], acc[1][bi], acc[2][bi], acc[3][bi]);
    *(float4*)&pout[(ksp * 32 + bb0 + bi) * 1024 + o] = rv;
  }
}

// ---------------- hred: h[b][o] = fc_b[o] + sum_j p_fc[j][b][o] ----------------
__global__ __launch_bounds__(256) void k_hred(
    const float* __restrict__ pfc, const float* __restrict__ fcb,
    float* __restrict__ h) {
  const int idx = blockIdx.x * 256 + threadIdx.x;
  const int b = idx >> 10, o = idx & 1023;
  float hv = fcb[o];
#pragma unroll 4
  for (int j = 0; j < 32; ++j) hv += pfc[(j * 32 + b) * 1024 + o];
  h[idx] = hv;
}

// ---------------- ff1: [32,1024] x [1024,1024]^T, reads h ----------------
// grid 256 = 16 o-blocks(64) x 16 k-splits(64)
__global__ __launch_bounds__(256) void k_ff1(
    const float* __restrict__ h, const float* __restrict__ w,
    float* __restrict__ pout) {
  __shared__ float xs[64 * 36];
  const int tid = threadIdx.x;
  const int ob = blockIdx.x & 15, ksp = blockIdx.x >> 4;
  const int k0 = ksp * 64, obase = ob * 64;
  for (int r = tid; r < 2048; r += 256) {
    int b = r >> 6, kk = r & 63;
    xs[kk * 36 + b] = h[b * 1024 + k0 + kk];
  }
  __syncthreads();
  const int og = tid & 15, bg = tid >> 4;
  const int o = obase + og * 4, bb0 = bg * 2;
  float acc[4][2] = {};
  const float* wp = w + o * 1024 + k0;
  for (int kk = 0; kk < 64; kk += 4) {
    float2 x0 = *(const float2*)&xs[(kk + 0) * 36 + bb0];
    float2 x1 = *(const float2*)&xs[(kk + 1) * 36 + bb0];
    float2 x2 = *(const float2*)&xs[(kk + 2) * 36 + bb0];
    float2 x3 = *(const float2*)&xs[(kk + 3) * 36 + bb0];
#pragma unroll
    for (int oo = 0; oo < 4; ++oo) {
      float4 wv = *(const float4*)(wp + oo * 1024 + kk);
      acc[oo][0] = fmaf(wv.x, x0.x, fmaf(wv.y, x1.x, fmaf(wv.z, x2.x, fmaf(wv.w, x3.x, acc[oo][0]))));
      acc[oo][1] = fmaf(wv.x, x0.y, fmaf(wv.y, x1.y, fmaf(wv.z, x2.y, fmaf(wv.w, x3.y, acc[oo][1]))));
    }
  }
#pragma unroll
  for (int bi = 0; bi < 2; ++bi) {
    float4 rv = make_float4(acc[0][bi], acc[1][bi], acc[2][bi], acc[3][bi]);
    *(float4*)&pout[(ksp * 32 + bb0 + bi) * 1024 + o] = rv;
  }
}

// ---------------- tail1 (per batch): LN+ELU+residual; ff2; gates; moe stage0 pre-bn ----------------
__global__ __launch_bounds__(256) void k_tail1(
    const float* __restrict__ h, const float* __restrict__ pff1,
    const float* __restrict__ ff1b,
    const float* __restrict__ lng, const float* __restrict__ lnb,
    const float* __restrict__ f2w, const float* __restrict__ f2b,
    const float* __restrict__ vp, const float* __restrict__ w0,
    const float* __restrict__ b0, float* __restrict__ wgate,
    float* __restrict__ s1pre) {
  __shared__ float hs[1024], ts[1024];
  __shared__ float mw_s[48];
  __shared__ float red2[4][2];
  __shared__ float bc[2];
  __shared__ float tot_s;
  const int b = blockIdx.x, tid = threadIdx.x;
  const int lane = tid & 63, wid = tid >> 6;
  for (int o = tid; o < 1024; o += 256) {
    hs[o] = h[b * 1024 + o];
    float tv = ff1b[o];
#pragma unroll 4
    for (int j = 0; j < 16; ++j) tv += pff1[(j * 32 + b) * 1024 + o];
    ts[o] = tv;
  }
  __syncthreads();
  float ls = 0.f, lss = 0.f;
  for (int o = tid; o < 1024; o += 256) {
    float t = ts[o];
    ls += t; lss += t * t;
  }
  ls = wred(ls); lss = wred(lss);
  if (lane == 0) { red2[wid][0] = ls; red2[wid][1] = lss; }
  __syncthreads();
  if (tid == 0) {
    float S = red2[0][0] + red2[1][0] + red2[2][0] + red2[3][0];
    float SS = red2[0][1] + red2[1][1] + red2[2][1] + red2[3][1];
    float m = S * (1.f / 1024.f);
    float var = SS * (1.f / 1024.f) - m * m;
    bc[0] = m; bc[1] = rsqrtf(var + EPSF);
  }
  __syncthreads();
  const float m = bc[0], inv = bc[1];
  for (int o = tid; o < 1024; o += 256) {
    float y = fmaf((ts[o] - m) * inv, lng[o], lnb[o]);
    float e = (y > 0.f) ? y : expm1f(y);
    ts[o] = hs[o] + e;  // h2
  }
  __syncthreads();
  if (tid < 192) {
    int e = tid >> 2, part = tid & 3;
    float acc = 0.f;
    const float* wr = f2w + e * 1024 + part * 4;
    for (int i = 0; i < 64; ++i) {
      float4 wv = *(const float4*)(wr + i * 16);
      int ob = i * 16 + part * 4;
      acc = fmaf(wv.x, ts[ob], fmaf(wv.y, ts[ob + 1], fmaf(wv.z, ts[ob + 2], fmaf(wv.w, ts[ob + 3], acc))));
    }
    acc += __shfl_down(acc, 1, 64);
    acc += __shfl_down(acc, 2, 64);
    if (part == 0) mw_s[e] = acc + f2b[e];
  }
  __syncthreads();
  if (tid < 64) {
    float v = (tid < 48) ? mw_s[tid] : 0.f;
    float t = wred(v);
    if (tid == 0) tot_s = t;
  }
  __syncthreads();
  if (tid < 48) {
    float wg = mw_s[tid] / tot_s;
    mw_s[tid] = wg;
    wgate[b * 48 + tid] = wg;
  }
  __syncthreads();
  if (tid < 32) {
    const int o = tid;
    const float v0 = vp[b * 3], v1 = vp[b * 3 + 1], v2 = vp[b * 3 + 2];
    float acc = 0.f;
#pragma unroll 4
    for (int e = 0; e < 48; ++e) {
      const float* wr = w0 + (e * 32 + o) * 3;
      float y = b0[e * 32 + o] + wr[0] * v0 + wr[1] * v1 + wr[2] * v2;
      acc = fmaf(mw_s[e], y, acc);
    }
    s1pre[b * 32 + o] = acc;
  }
}

// ---------------- moe1 (b x expert-chunk): bn over batch (redundant) + prelu + partial gated sum ----------------
// grid 256 = 32 b x 8 chunks of 6 experts; pmoe[ech][b][op] partials, reduced in k_final.
__global__ __launch_bounds__(128) void k_moe1(
    const float* __restrict__ s1pre, const float* __restrict__ g0,
    const float* __restrict__ be0, const float* __restrict__ pf_p,
    const float* __restrict__ wgate, const float* __restrict__ w1,
    const float* __restrict__ b1, float* __restrict__ pmoe) {
  __shared__ float s1n[32];
  __shared__ float wgs[6];
  const int tid = threadIdx.x;
  const int b = blockIdx.x >> 3, ech = blockIdx.x & 7;
  const int e0 = ech * 6;
  const float pf = pf_p[0];
  if (tid < 6) wgs[tid] = wgate[b * 48 + e0 + tid];
  if (tid < 32) {
    const int o = tid;
    float s = 0.f, ss = 0.f;
    for (int bb = 0; bb < 32; ++bb) {
      float v = s1pre[bb * 32 + o];
      s += v; ss += v * v;
    }
    float mm = s * (1.f / 32.f);
    float var = ss * (1.f / 32.f) - mm * mm;
    float a = g0[o] * rsqrtf(var + EPSF);
    float c = be0[o] - mm * a;
    float v = fmaf(s1pre[b * 32 + o], a, c);
    s1n[o] = (v >= 0.f) ? v : pf * v;
  }
  __syncthreads();
  const int op = tid;  // 0..127
  float acc = 0.f;
#pragma unroll
  for (int ee = 0; ee < 6; ++ee) {
    const int e = e0 + ee;
    const float* wr = w1 + (e * 128 + op) * 32;
    float y = b1[e * 128 + op];
#pragma unroll
    for (int i = 0; i < 32; i += 4) {
      float4 wv = *(const float4*)(wr + i);
      y = fmaf(wv.x, s1n[i], fmaf(wv.y, s1n[i + 1], fmaf(wv.z, s1n[i + 2], fmaf(wv.w, s1n[i + 3], y))));
    }
    acc = fmaf(wgs[ee], y, acc);
  }
  pmoe[ech * 4096 + b * 128 + op] = acc;
}

// ---------------- final: reduce 8 moe partials; bn over batch + prelu + dot(128) + sigmoid ----------------
__global__ __launch_bounds__(256) void k_final(
    const float* __restrict__ pmoe, const float* __restrict__ g1,
    const float* __restrict__ be1, const float* __restrict__ pf_p,
    const float* __restrict__ ow, const float* __restrict__ obp,
    float* __restrict__ outp) {
  __shared__ float s2[32 * 132];
  __shared__ float ca[128], cb[128];
  const int tid = threadIdx.x;
  for (int r = tid; r < 4096; r += 256) {
    int b = r >> 7, o = r & 127;
    float v = 0.f;
#pragma unroll
    for (int j = 0; j < 8; ++j) v += pmoe[j * 4096 + r];
    s2[b * 132 + o] = v;
  }
  __syncthreads();
  if (tid < 128) {
    const int o = tid;
    float s = 0.f, ss = 0.f;
    for (int b = 0; b < 32; ++b) {
      float v = s2[b * 132 + o];
      s += v; ss += v * v;
    }
    float mm = s * (1.f / 32.f);
    float var = ss * (1.f / 32.f) - mm * mm;
    float a = g1[o] * rsqrtf(var + EPSF);
    ca[o] = a; cb[o] = be1[o] - mm * a;
  }
  __syncthreads();
  const float pf = pf_p[0];
  if (tid < 32) {
    const int b = tid;
    float acc = 0.f;
#pragma unroll 4
    for (int o = 0; o < 128; ++o) {
      float v = fmaf(s2[b * 132 + o], ca[o], cb[o]);
      v = (v >= 0.f) ? v : pf * v;
      acc = fmaf(v, ow[o], acc);
    }
    float z = acc + obp[0];
    outp[b] = 1.f / (1.f + __expf(-z));
  }
}

// ---------------- launch ----------------
extern "C" void kernel_launch(void* const* d_in, const int* in_sizes, int n_in,
                              void* d_out, int out_size, void* d_ws, size_t ws_size,
                              hipStream_t stream) {
  (void)in_sizes; (void)n_in; (void)out_size; (void)ws_size;
  const float* vertex_pos = (const float*)d_in[0];
  const float* body_mesh  = (const float*)d_in[1];
  const float* conv1_w    = (const float*)d_in[2];
  const float* conv1_b    = (const float*)d_in[3];
  const float* bn1_g      = (const float*)d_in[4];
  const float* bn1_b      = (const float*)d_in[5];
  const float* conv2_w    = (const float*)d_in[6];
  const float* conv2_b    = (const float*)d_in[7];
  const float* bn2_g      = (const float*)d_in[8];
  const float* bn2_b      = (const float*)d_in[9];
  const float* prelu_a    = (const float*)d_in[10];
  const float* wq = (const float*)d_in[11]; const float* bq = (const float*)d_in[12];
  const float* wk = (const float*)d_in[13]; const float* bk = (const float*)d_in[14];
  const float* wv = (const float*)d_in[15]; const float* bv = (const float*)d_in[16];
  const float* fc_w  = (const float*)d_in[17]; const float* fc_b  = (const float*)d_in[18];
  const float* ff1_w = (const float*)d_in[19]; const float* ff1_b = (const float*)d_in[20];
  const float* ln_g  = (const float*)d_in[21]; const float* ln_b  = (const float*)d_in[22];
  const float* ff2_w = (const float*)d_in[23]; const float* ff2_b = (const float*)d_in[24];
  const float* fus_w0 = (const float*)d_in[25]; const float* fus_b0 = (const float*)d_in[26];
  const float* fus_w1 = (const float*)d_in[27]; const float* fus_b1 = (const float*)d_in[28];
  const float* bnf0_g = (const float*)d_in[29]; const float* bnf0_b = (const float*)d_in[30];
  const float* bnf1_g = (const float*)d_in[31]; const float* bnf1_b = (const float*)d_in[32];
  const float* prelu_f = (const float*)d_in[33];
  const float* out_w = (const float*)d_in[34]; const float* out_b = (const float*)d_in[35];

  float* ws = (float*)d_ws;
  float* conv1_out = ws + 0;        // 326496
  float* conv2_out = ws + 326496;   // -> 621408
  float* qws = ws + 621408;         // -> 752480
  float* kws = ws + 752480;         // -> 883552
  float* vws = ws + 883552;         // -> 1014624
  float* p_fc = ws + 0;             // 1048576 (overlays region A; dead by k_fc)
  float* av    = ws + 1048576;      // -> 1179648
  float* hbuf  = ws + 1179648;      // -> 1212416
  float* p_ff1 = ws + 1212416;      // -> 1736704
  float* part1 = ws + 1736704;      // 6*864 -> 1741888
  float* part2 = ws + 1741888;      // 6*192 -> 1746496
  float* wgate = ws + 1746496;      // -> 1748032
  float* s1pre = ws + 1748032;      // -> 1749056
  float* pmoe  = ws + 1749056;      // 8*4096 -> 1781824 floats (~7.1 MB)

  k_conv1<<<864, 256, 0, stream>>>(body_mesh, conv1_w, conv1_b, conv1_out, part1);
  k_conv2<<<192, 256, 0, stream>>>(conv1_out, part1, bn1_g, bn1_b, conv2_w, conv2_b, conv2_out, part2);
  k_qkv<<<128, 256, 0, stream>>>(conv2_out, part2, bn2_g, bn2_b, prelu_a,
                                 wq, bq, wk, bk, wv, bv, qws, kws, vws);
  k_attn<<<512, 256, 0, stream>>>(qws, kws, vws, av);
  k_fc<<<512, 256, 0, stream>>>(av, fc_w, p_fc);
  k_hred<<<128, 256, 0, stream>>>(p_fc, fc_b, hbuf);
  k_ff1<<<256, 256, 0, stream>>>(hbuf, ff1_w, p_ff1);
  k_tail1<<<32, 256, 0, stream>>>(hbuf, p_ff1, ff1_b, ln_g, ln_b, ff2_w, ff2_b,
                                  vertex_pos, fus_w0, fus_b0, wgate, s1pre);
  k_moe1<<<256, 128, 0, stream>>>(s1pre, bnf0_g, bnf0_b, prelu_f, wgate, fus_w1, fus_b1, pmoe);
  k_final<<<1, 256, 0, stream>>>(pmoe, bnf1_g, bnf1_b, prelu_f, out_w, out_b, (float*)d_out);
}

// Round 10
// 315.613 us; speedup vs baseline: 1.3270x; 1.0261x over previous
//
#include <hip/hip_runtime.h>

#define EPSF 1e-5f

// ---------------- helpers ----------------
__device__ __forceinline__ float wred(float v) {
#pragma unroll
  for (int off = 32; off > 0; off >>= 1) v += __shfl_down(v, off, 64);
  return v;
}

// ---------------- wprep: transpose conv1 weights into global ws ----------------
// wTg[(c*18+u)*72 + t] = cw[c*1227 + 18t + u], zero when 18t+u >= 1227
__global__ __launch_bounds__(256) void k_wprep(
    const float* __restrict__ cw, float* __restrict__ wTg) {
  const int j = blockIdx.x * 256 + threadIdx.x;
  if (j < 3888) {
    int c = j / 1296, rem = j - c * 1296;
    int u = rem / 72, t = rem - u * 72;
    int i = 18 * t + u;
    wTg[j] = (i < 1227) ? cw[c * 1227 + i] : 0.f;
  }
}

// ---------------- conv1: u-planes in LDS, weights via SCALAR loads from wTg ----------------
// out[c][oh] = cb[c] + sum_u sum_t wTg[c][u][t] * P_u[oh+t],  P_u[p] = mesh[(oh0+p)*18+u].
// 256 outputs/block = 64 slots x 4 consecutive; wave-uniform u-chunks (kc = tid>>6):
// kc gets u in {4kc..4kc+3} plus {16+kc} for kc<2. x-reads: contiguous 1KB b128/wave.
__global__ __launch_bounds__(256) void k_conv1(
    const float* __restrict__ mesh, const float* __restrict__ wTg,
    const float* __restrict__ cb, float* __restrict__ out,
    float* __restrict__ part) {
  __shared__ float P[5976];     // 18 planes x 332
  __shared__ float red[3072];   // 4 chunks x 256 outs x 3 ch
  __shared__ float pm2[768];
  __shared__ float redm[4][6];
  const int tid = threadIdx.x;
  const int tile = blockIdx.x % 14, b = blockIdx.x / 14;
  const int oh0 = tile << 8;
  const int nvalid = min(256, 3401 - oh0);
  // stage planes: P[u*332 + p] = mesh[b*62439 + oh0*18 + 18p + u] (coalesced in j)
  {
    const int zoff = oh0 * 18;
    const float* src = mesh + b * 62439 + zoff;
    const int zmax = 62439 - zoff;
    for (int j = tid; j < 5976; j += 256) {
      int p = j / 18, u = j - p * 18;
      P[u * 332 + p] = (j < zmax) ? src[j] : 0.f;
    }
  }
  __syncthreads();
  const int kc = __builtin_amdgcn_readfirstlane(tid >> 6);
  const int s = tid & 63;
  const int xb = s << 2;
  const int nu = (kc < 2) ? 5 : 4;
  float acc[3][4] = {};
  for (int ui = 0; ui < nu; ++ui) {
    const int u = (ui < 4) ? (kc * 4 + ui) : (16 + kc);
    const float* Pu = P + u * 332 + xb;
    const float* wg = wTg + u * 72;   // uniform -> scalar loads
    float4 cur = *(const float4*)(Pu);
    float4 nxt = *(const float4*)(Pu + 4);
#pragma unroll
    for (int tg = 0; tg < 72; tg += 4) {
      float4 w0 = *(const float4*)(wg + tg);
      float4 w1 = *(const float4*)(wg + 1296 + tg);
      float4 w2 = *(const float4*)(wg + 2592 + tg);
      float x0 = cur.x, x1 = cur.y, x2 = cur.z, x3 = cur.w;
      float x4 = nxt.x, x5 = nxt.y, x6 = nxt.z;
      acc[0][0] = fmaf(w0.x, x0, fmaf(w0.y, x1, fmaf(w0.z, x2, fmaf(w0.w, x3, acc[0][0]))));
      acc[0][1] = fmaf(w0.x, x1, fmaf(w0.y, x2, fmaf(w0.z, x3, fmaf(w0.w, x4, acc[0][1]))));
      acc[0][2] = fmaf(w0.x, x2, fmaf(w0.y, x3, fmaf(w0.z, x4, fmaf(w0.w, x5, acc[0][2]))));
      acc[0][3] = fmaf(w0.x, x3, fmaf(w0.y, x4, fmaf(w0.z, x5, fmaf(w0.w, x6, acc[0][3]))));
      acc[1][0] = fmaf(w1.x, x0, fmaf(w1.y, x1, fmaf(w1.z, x2, fmaf(w1.w, x3, acc[1][0]))));
      acc[1][1] = fmaf(w1.x, x1, fmaf(w1.y, x2, fmaf(w1.z, x3, fmaf(w1.w, x4, acc[1][1]))));
      acc[1][2] = fmaf(w1.x, x2, fmaf(w1.y, x3, fmaf(w1.z, x4, fmaf(w1.w, x5, acc[1][2]))));
      acc[1][3] = fmaf(w1.x, x3, fmaf(w1.y, x4, fmaf(w1.z, x5, fmaf(w1.w, x6, acc[1][3]))));
      acc[2][0] = fmaf(w2.x, x0, fmaf(w2.y, x1, fmaf(w2.z, x2, fmaf(w2.w, x3, acc[2][0]))));
      acc[2][1] = fmaf(w2.x, x1, fmaf(w2.y, x2, fmaf(w2.z, x3, fmaf(w2.w, x4, acc[2][1]))));
      acc[2][2] = fmaf(w2.x, x2, fmaf(w2.y, x3, fmaf(w2.z, x4, fmaf(w2.w, x5, acc[2][2]))));
      acc[2][3] = fmaf(w2.x, x3, fmaf(w2.y, x4, fmaf(w2.z, x5, fmaf(w2.w, x6, acc[2][3]))));
      cur = nxt;
      nxt = *(const float4*)(Pu + tg + 8);
    }
  }
  // red[kc][out*3 + ch], out = s*4 + r
#pragma unroll
  for (int r = 0; r < 4; ++r)
#pragma unroll
    for (int ch = 0; ch < 3; ++ch)
      red[kc * 768 + (xb + r) * 3 + ch] = acc[ch][r];
  __syncthreads();
#pragma unroll
  for (int q = 0; q < 3; ++q) {
    const int combo = q * 256 + tid;
    float v = cb[combo % 3];
#pragma unroll
    for (int c2 = 0; c2 < 4; ++c2) v += red[c2 * 768 + combo];
    pm2[combo] = v;
  }
  __syncthreads();
  float st[6] = {0.f, 0.f, 0.f, 0.f, 0.f, 0.f};
  if (tid < nvalid) {
    float y0 = pm2[tid * 3 + 0];
    float y1 = pm2[tid * 3 + 1];
    float y2 = pm2[tid * 3 + 2];
    float* op = out + b * 10203 + oh0 + tid;
    op[0] = y0; op[3401] = y1; op[6802] = y2;
    st[0] = y0; st[1] = y0 * y0; st[2] = y1; st[3] = y1 * y1; st[4] = y2; st[5] = y2 * y2;
  }
  const int lane = tid & 63, wid = tid >> 6;
#pragma unroll
  for (int c = 0; c < 6; ++c) {
    float rv = wred(st[c]);
    if (lane == 0) redm[wid][c] = rv;
  }
  __syncthreads();
  if (tid < 6)
    part[tid * 448 + blockIdx.x] = redm[0][tid] + redm[1][tid] + redm[2][tid] + redm[3][tid];
}

// ---------------- conv2: u-plane decomposition, fully aligned LDS reads ----------------
__global__ __launch_bounds__(256) void k_conv2(
    const float* __restrict__ x1, const float* __restrict__ part1,
    const float* __restrict__ g1, const float* __restrict__ be1,
    const float* __restrict__ cw, const float* __restrict__ cb,
    float* __restrict__ out, float* __restrict__ part) {
  __shared__ float wT[3024];      // [u][c][t] rows of 336, zero-padded t>=330
  __shared__ float P[3][852];     // input planes
  __shared__ float red[1536];     // kc1 partials: 128 slots x 12
  __shared__ float redm[4][6];
  __shared__ float coef[6];
  const int tid = threadIdx.x;
  const int lane = tid & 63, wid = tid >> 6;
  {  // reduce conv1 stats (transposed: part1[c*448 + blk]) -> bn1 coefficients
    float r6[6] = {0.f, 0.f, 0.f, 0.f, 0.f, 0.f};
    for (int j = tid; j < 448; j += 256) {
#pragma unroll
      for (int c = 0; c < 6; ++c) r6[c] += part1[c * 448 + j];
    }
#pragma unroll
    for (int c = 0; c < 6; ++c) {
      float rv = wred(r6[c]);
      if (lane == 0) redm[wid][c] = rv;
    }
    __syncthreads();
    if (tid == 0) {
      const float inv_n = 1.f / (32.f * 3401.f);
#pragma unroll
      for (int c = 0; c < 3; ++c) {
        float s = redm[0][2 * c] + redm[1][2 * c] + redm[2][2 * c] + redm[3][2 * c];
        float ss = redm[0][2 * c + 1] + redm[1][2 * c + 1] + redm[2][2 * c + 1] + redm[3][2 * c + 1];
        float m = s * inv_n;
        float var = ss * inv_n - m * m;
        float a = g1[c] * rsqrtf(var + EPSF);
        coef[c] = a; coef[3 + c] = be1[c] - m * a;
      }
    }
  }
  // stage transposed weights: wT[u*1008 + c*336 + t] = cw[c*990 + 3t + u], 0 for t>=330
  for (int j = tid; j < 3024; j += 256) {
    int u = j / 1008, rem = j - u * 1008;
    int c = rem / 336, t = rem - c * 336;
    wT[j] = (t < 330) ? cw[c * 990 + 3 * t + u] : 0.f;
  }
  __syncthreads();  // coef + wT ready
  const int tile = blockIdx.x % 6, b = blockIdx.x / 6;
  const int oh0 = tile << 9;
  const int zbase = oh0 * 3;
  const float* src = x1 + b * 10203 + zbase;
  // stage bn1-transformed planes (coalesced global reads)
  for (int j = tid; j < 2556; j += 256) {
    int rel = j / 3, u = j - rel * 3;
    float val = 0.f;
    int z = zbase + j;
    if (z <= 10202) {
      int c = (z >= 6802) ? 2 : ((z >= 3401) ? 1 : 0);
      val = fmaf(coef[c], src[j], coef[3 + c]);
    }
    P[u][rel] = val;
  }
  __syncthreads();
  const int kc = tid >> 7, s = tid & 127;
  const int t0 = kc * 168;
  const int xb = s << 2;
  float acc0[4] = {}, acc1[4] = {}, acc2[4] = {};
  float4 cur0 = *(const float4*)&P[0][xb + t0];
  float4 cur1 = *(const float4*)&P[1][xb + t0];
  float4 cur2 = *(const float4*)&P[2][xb + t0];
  float4 nxt0 = *(const float4*)&P[0][xb + t0 + 4];
  float4 nxt1 = *(const float4*)&P[1][xb + t0 + 4];
  float4 nxt2 = *(const float4*)&P[2][xb + t0 + 4];
  const int tend = t0 + 168;
  for (int tg = t0; tg < tend; tg += 4) {
#define CONV2_U(ACC0, ACC1, ACC2, UOFF, CUR, NXT)                                                  \
    {                                                                                              \
      const float* wu = wT + UOFF + tg;                                                            \
      float2 wa0 = *(const float2*)(wu);                                                           \
      float2 wb0 = *(const float2*)(wu + 2);                                                       \
      float2 wa1 = *(const float2*)(wu + 336);                                                     \
      float2 wb1 = *(const float2*)(wu + 338);                                                     \
      float2 wa2 = *(const float2*)(wu + 672);                                                     \
      float2 wb2 = *(const float2*)(wu + 674);                                                     \
      float x0 = CUR.x, x1v = CUR.y, x2v = CUR.z, x3v = CUR.w;                                     \
      float x4 = NXT.x, x5 = NXT.y, x6 = NXT.z;                                                    \
      ACC0[0] = fmaf(wa0.x, x0,  fmaf(wa0.y, x1v, fmaf(wb0.x, x2v, fmaf(wb0.y, x3v, ACC0[0]))));  \
      ACC0[1] = fmaf(wa0.x, x1v, fmaf(wa0.y, x2v, fmaf(wb0.x, x3v, fmaf(wb0.y, x4,  ACC0[1]))));  \
      ACC0[2] = fmaf(wa0.x, x2v, fmaf(wa0.y, x3v, fmaf(wb0.x, x4,  fmaf(wb0.y, x5,  ACC0[2]))));  \
      ACC0[3] = fmaf(wa0.x, x3v, fmaf(wa0.y, x4,  fmaf(wb0.x, x5,  fmaf(wb0.y, x6,  ACC0[3]))));  \
      ACC1[0] = fmaf(wa1.x, x0,  fmaf(wa1.y, x1v, fmaf(wb1.x, x2v, fmaf(wb1.y, x3v, ACC1[0]))));  \
      ACC1[1] = fmaf(wa1.x, x1v, fmaf(wa1.y, x2v, fmaf(wb1.x, x3v, fmaf(wb1.y, x4,  ACC1[1]))));  \
      ACC1[2] = fmaf(wa1.x, x2v, fmaf(wa1.y, x3v, fmaf(wb1.x, x4,  fmaf(wb1.y, x5,  ACC1[2]))));  \
      ACC1[3] = fmaf(wa1.x, x3v, fmaf(wa1.y, x4,  fmaf(wb1.x, x5,  fmaf(wb1.y, x6,  ACC1[3]))));  \
      ACC2[0] = fmaf(wa2.x, x0,  fmaf(wa2.y, x1v, fmaf(wb2.x, x2v, fmaf(wb2.y, x3v, ACC2[0]))));  \
      ACC2[1] = fmaf(wa2.x, x1v, fmaf(wa2.y, x2v, fmaf(wb2.x, x3v, fmaf(wb2.y, x4,  ACC2[1]))));  \
      ACC2[2] = fmaf(wa2.x, x2v, fmaf(wa2.y, x3v, fmaf(wb2.x, x4,  fmaf(wb2.y, x5,  ACC2[2]))));  \
      ACC2[3] = fmaf(wa2.x, x3v, fmaf(wa2.y, x4,  fmaf(wb2.x, x5,  fmaf(wb2.y, x6,  ACC2[3]))));  \
    }
    CONV2_U(acc0, acc1, acc2, 0,    cur0, nxt0)
    CONV2_U(acc0, acc1, acc2, 1008, cur1, nxt1)
    CONV2_U(acc0, acc1, acc2, 2016, cur2, nxt2)
#undef CONV2_U
    cur0 = nxt0; cur1 = nxt1; cur2 = nxt2;
    nxt0 = *(const float4*)&P[0][xb + tg + 8];
    nxt1 = *(const float4*)&P[1][xb + tg + 8];
    nxt2 = *(const float4*)&P[2][xb + tg + 8];
  }
  if (kc == 1) {
#pragma unroll
    for (int r = 0; r < 4; ++r) {
      red[s * 12 + r] = acc0[r];
      red[s * 12 + 4 + r] = acc1[r];
      red[s * 12 + 8 + r] = acc2[r];
    }
  }
  __syncthreads();
  float st[6] = {0.f, 0.f, 0.f, 0.f, 0.f, 0.f};
  if (kc == 0) {
    float y0[4], y1[4], y2[4];
#pragma unroll
    for (int r = 0; r < 4; ++r) {
      y0[r] = acc0[r] + red[s * 12 + r] + cb[0];
      y1[r] = acc1[r] + red[s * 12 + 4 + r] + cb[1];
      y2[r] = acc2[r] + red[s * 12 + 8 + r] + cb[2];
      st[0] += y0[r]; st[1] += y0[r] * y0[r];
      st[2] += y1[r]; st[3] += y1[r] * y1[r];
      st[4] += y2[r]; st[5] += y2[r] * y2[r];
    }
    float* op = out + b * 9216 + oh0 + xb;
    *(float4*)(op)        = make_float4(y0[0], y0[1], y0[2], y0[3]);
    *(float4*)(op + 3072) = make_float4(y1[0], y1[1], y1[2], y1[3]);
    *(float4*)(op + 6144) = make_float4(y2[0], y2[1], y2[2], y2[3]);
  }
#pragma unroll
  for (int c = 0; c < 6; ++c) {
    float rv = wred(st[c]);
    if (lane == 0) redm[wid][c] = rv;
  }
  __syncthreads();
  if (tid < 6)
    part[tid * 192 + blockIdx.x] = redm[0][tid] + redm[1][tid] + redm[2][tid] + redm[3][tid];
}

// ---------------- qkv: bn2 + prelu + 3x (9->4) ; q scaled by 1/sqrt(2)*log2(e) ----------------
__global__ __launch_bounds__(256) void k_qkv(
    const float* __restrict__ x2, const float* __restrict__ part2,
    const float* __restrict__ g2, const float* __restrict__ be2,
    const float* __restrict__ pa_p,
    const float* __restrict__ wq, const float* __restrict__ bq,
    const float* __restrict__ wk, const float* __restrict__ bk,
    const float* __restrict__ wv, const float* __restrict__ bv,
    float* __restrict__ qo, float* __restrict__ ko, float* __restrict__ vo) {
  __shared__ float redm[4][6];
  __shared__ float coef[6];
  const int tid = threadIdx.x;
  const int lane = tid & 63, wid = tid >> 6;
  {
    float r[6] = {0.f, 0.f, 0.f, 0.f, 0.f, 0.f};
    for (int j = tid; j < 192; j += 256) {
#pragma unroll
      for (int c = 0; c < 6; ++c) r[c] += part2[c * 192 + j];
    }
#pragma unroll
    for (int c = 0; c < 6; ++c) {
      float rv = wred(r[c]);
      if (lane == 0) redm[wid][c] = rv;
    }
    __syncthreads();
    if (tid == 0) {
      const float inv_n = 1.f / (32.f * 3072.f);
#pragma unroll
      for (int c = 0; c < 3; ++c) {
        float s = redm[0][2 * c] + redm[1][2 * c] + redm[2][2 * c] + redm[3][2 * c];
        float ss = redm[0][2 * c + 1] + redm[1][2 * c + 1] + redm[2][2 * c + 1] + redm[3][2 * c + 1];
        float m = s * inv_n;
        float var = ss * inv_n - m * m;
        float a = g2[c] * rsqrtf(var + EPSF);
        coef[c] = a; coef[3 + c] = be2[c] - m * a;
      }
    }
    __syncthreads();
  }
  const float pa = pa_p[0];
  const int id = blockIdx.x * 256 + tid;
  const int b = id >> 10, f = id & 1023;
  const float* src = x2 + b * 9216 + f * 9;
  float x[9];
  const int z0 = f * 9;
#pragma unroll
  for (int j = 0; j < 9; ++j) {
    int z = z0 + j;
    int c = (z >= 6144) ? 2 : ((z >= 3072) ? 1 : 0);
    float v = fmaf(coef[c], src[j], coef[3 + c]);
    x[j] = (v >= 0.f) ? v : pa * v;
  }
  const float QSCALE = 0.70710678118654752f * 1.44269504088896341f;  // 1/sqrt(HD) * log2(e)
#pragma unroll
  for (int dd = 0; dd < 4; ++dd) {
    float q = bq[dd], k = bk[dd], v = bv[dd];
#pragma unroll
    for (int j = 0; j < 9; ++j) {
      q = fmaf(wq[dd * 9 + j], x[j], q);
      k = fmaf(wk[dd * 9 + j], x[j], k);
      v = fmaf(wv[dd * 9 + j], x[j], v);
    }
    int hh = dd >> 1, d = dd & 1;
    int idx = ((b * 2 + hh) * 1024 + f) * 2 + d;
    qo[idx] = q * QSCALE;
    ko[idx] = k;
    vo[idx] = v;
  }
}

// ---------------- attention: per (b,h) softmax(qk)v, HD=2; bound-max single pass ----------------
__device__ __forceinline__ int kvIdx(int j) { return j + (j >> 7); }

__global__ __launch_bounds__(256) void k_attn(
    const float* __restrict__ q, const float* __restrict__ k,
    const float* __restrict__ v, float* __restrict__ av) {
  __shared__ float4 kv[1032];
  __shared__ float smax[4];
  const int tid = threadIdx.x;
  const int bh = blockIdx.x >> 3, rblk = blockIdx.x & 7;
  const float2* kp = (const float2*)(k + bh * 2048);
  const float2* vp = (const float2*)(v + bh * 2048);
  float nkm = 0.f;
  for (int j = tid; j < 1024; j += 256) {
    float2 kk = kp[j], vv = vp[j];
    kv[kvIdx(j)] = make_float4(kk.x, kk.y, vv.x, vv.y);
    nkm = fmaxf(nkm, fmaf(kk.x, kk.x, kk.y * kk.y));
  }
#pragma unroll
  for (int off = 32; off > 0; off >>= 1) nkm = fmaxf(nkm, __shfl_xor(nkm, off, 64));
  if ((tid & 63) == 0) smax[tid >> 6] = nkm;
  __syncthreads();
  const float knorm = sqrtf(fmaxf(fmaxf(smax[0], smax[1]), fmaxf(smax[2], smax[3])));
  const int lane = tid & 63, w = tid >> 6;
  const int rg = (w << 3) | (lane >> 3);
  const int ks = lane & 7;
  const int r0 = rblk * 128 + rg * 4;
  const float4 q01 = *(const float4*)(q + (bh * 1024 + r0) * 2);
  const float4 q23 = *(const float4*)(q + (bh * 1024 + r0) * 2 + 4);
  float qx[4] = {q01.x, q01.z, q23.x, q23.z};
  float qy[4] = {q01.y, q01.w, q23.y, q23.w};
  float m[4], l[4] = {0.f, 0.f, 0.f, 0.f};
  float o0[4] = {0.f, 0.f, 0.f, 0.f}, o1[4] = {0.f, 0.f, 0.f, 0.f};
#pragma unroll
  for (int r = 0; r < 4; ++r) m[r] = sqrtf(fmaf(qx[r], qx[r], qy[r] * qy[r])) * knorm;
  const int j0 = ks * 128;
#pragma unroll 4
  for (int jj = 0; jj < 128; ++jj) {
    float4 kk = kv[kvIdx(j0 + jj)];
#pragma unroll
    for (int r = 0; r < 4; ++r) {
      float s = fmaf(qx[r], kk.x, qy[r] * kk.y);
      float p = exp2f(s - m[r]);
      l[r] += p;
      o0[r] = fmaf(p, kk.z, o0[r]);
      o1[r] = fmaf(p, kk.w, o1[r]);
    }
  }
#pragma unroll
  for (int off = 1; off <= 4; off <<= 1) {
#pragma unroll
    for (int r = 0; r < 4; ++r) {
      l[r] += __shfl_xor(l[r], off, 64);
      o0[r] += __shfl_xor(o0[r], off, 64);
      o1[r] += __shfl_xor(o1[r], off, 64);
    }
  }
  if (ks == 0) {
    const int b = bh >> 1, hh = bh & 1;
#pragma unroll
    for (int r = 0; r < 4; ++r) {
      float rl = 1.f / l[r];
      *(float2*)(av + b * 4096 + (r0 + r) * 4 + hh * 2) = make_float2(o0[r] * rl, o1[r] * rl);
    }
  }
}

// ---------------- fc: [32,4096] x [1024,4096]^T, K-split partials ----------------
// grid 512 = 16 o-blocks(64) x 32 k-splits(128); thread = 4o x 2b
__global__ __launch_bounds__(256) void k_fc(
    const float* __restrict__ x, const float* __restrict__ w,
    float* __restrict__ pout) {
  __shared__ float xs[128 * 36];
  const int tid = threadIdx.x;
  const int ob = blockIdx.x & 15, ksp = blockIdx.x >> 4;
  const int k0 = ksp * 128, obase = ob * 64;
  for (int r = tid; r < 4096; r += 256) {
    int b = r >> 7, kk = r & 127;
    xs[kk * 36 + b] = x[b * 4096 + k0 + kk];
  }
  __syncthreads();
  const int og = tid & 15, bg = tid >> 4;
  const int o = obase + og * 4, bb0 = bg * 2;
  float acc[4][2] = {};
  const float* wp = w + o * 4096 + k0;
  for (int kk = 0; kk < 128; kk += 4) {
    float2 x0 = *(const float2*)&xs[(kk + 0) * 36 + bb0];
    float2 x1 = *(const float2*)&xs[(kk + 1) * 36 + bb0];
    float2 x2 = *(const float2*)&xs[(kk + 2) * 36 + bb0];
    float2 x3 = *(const float2*)&xs[(kk + 3) * 36 + bb0];
#pragma unroll
    for (int oo = 0; oo < 4; ++oo) {
      float4 wv = *(const float4*)(wp + oo * 4096 + kk);
      acc[oo][0] = fmaf(wv.x, x0.x, fmaf(wv.y, x1.x, fmaf(wv.z, x2.x, fmaf(wv.w, x3.x, acc[oo][0]))));
      acc[oo][1] = fmaf(wv.x, x0.y, fmaf(wv.y, x1.y, fmaf(wv.z, x2.y, fmaf(wv.w, x3.y, acc[oo][1]))));
    }
  }
#pragma unroll
  for (int bi = 0; bi < 2; ++bi) {
    float4 rv = make_float4(acc[0][bi], acc[1][bi], acc[2][bi], acc[3][bi]);
    *(float4*)&pout[(ksp * 32 + bb0 + bi) * 1024 + o] = rv;
  }
}

// ---------------- hred: h[b][o] = fc_b[o] + sum_j p_fc[j][b][o] ----------------
__global__ __launch_bounds__(256) void k_hred(
    const float* __restrict__ pfc, const float* __restrict__ fcb,
    float* __restrict__ h) {
  const int idx = blockIdx.x * 256 + threadIdx.x;
  const int b = idx >> 10, o = idx & 1023;
  float hv = fcb[o];
#pragma unroll 4
  for (int j = 0; j < 32; ++j) hv += pfc[(j * 32 + b) * 1024 + o];
  h[idx] = hv;
}

// ---------------- ff1: [32,1024] x [1024,1024]^T, reads h ----------------
// grid 256 = 16 o-blocks(64) x 16 k-splits(64)
__global__ __launch_bounds__(256) void k_ff1(
    const float* __restrict__ h, const float* __restrict__ w,
    float* __restrict__ pout) {
  __shared__ float xs[64 * 36];
  const int tid = threadIdx.x;
  const int ob = blockIdx.x & 15, ksp = blockIdx.x >> 4;
  const int k0 = ksp * 64, obase = ob * 64;
  for (int r = tid; r < 2048; r += 256) {
    int b = r >> 6, kk = r & 63;
    xs[kk * 36 + b] = h[b * 1024 + k0 + kk];
  }
  __syncthreads();
  const int og = tid & 15, bg = tid >> 4;
  const int o = obase + og * 4, bb0 = bg * 2;
  float acc[4][2] = {};
  const float* wp = w + o * 1024 + k0;
  for (int kk = 0; kk < 64; kk += 4) {
    float2 x0 = *(const float2*)&xs[(kk + 0) * 36 + bb0];
    float2 x1 = *(const float2*)&xs[(kk + 1) * 36 + bb0];
    float2 x2 = *(const float2*)&xs[(kk + 2) * 36 + bb0];
    float2 x3 = *(const float2*)&xs[(kk + 3) * 36 + bb0];
#pragma unroll
    for (int oo = 0; oo < 4; ++oo) {
      float4 wv = *(const float4*)(wp + oo * 1024 + kk);
      acc[oo][0] = fmaf(wv.x, x0.x, fmaf(wv.y, x1.x, fmaf(wv.z, x2.x, fmaf(wv.w, x3.x, acc[oo][0]))));
      acc[oo][1] = fmaf(wv.x, x0.y, fmaf(wv.y, x1.y, fmaf(wv.z, x2.y, fmaf(wv.w, x3.y, acc[oo][1]))));
    }
  }
#pragma unroll
  for (int bi = 0; bi < 2; ++bi) {
    float4 rv = make_float4(acc[0][bi], acc[1][bi], acc[2][bi], acc[3][bi]);
    *(float4*)&pout[(ksp * 32 + bb0 + bi) * 1024 + o] = rv;
  }
}

// ---------------- tail1 (per batch): LN+ELU+residual; ff2; gates; moe stage0 pre-bn ----------------
__global__ __launch_bounds__(256) void k_tail1(
    const float* __restrict__ h, const float* __restrict__ pff1,
    const float* __restrict__ ff1b,
    const float* __restrict__ lng, const float* __restrict__ lnb,
    const float* __restrict__ f2w, const float* __restrict__ f2b,
    const float* __restrict__ vp, const float* __restrict__ w0,
    const float* __restrict__ b0, float* __restrict__ wgate,
    float* __restrict__ s1pre) {
  __shared__ float hs[1024], ts[1024];
  __shared__ float mw_s[48];
  __shared__ float red2[4][2];
  __shared__ float bc[2];
  __shared__ float tot_s;
  const int b = blockIdx.x, tid = threadIdx.x;
  const int lane = tid & 63, wid = tid >> 6;
  for (int o = tid; o < 1024; o += 256) {
    hs[o] = h[b * 1024 + o];
    float tv = ff1b[o];
#pragma unroll 4
    for (int j = 0; j < 16; ++j) tv += pff1[(j * 32 + b) * 1024 + o];
    ts[o] = tv;
  }
  __syncthreads();
  float ls = 0.f, lss = 0.f;
  for (int o = tid; o < 1024; o += 256) {
    float t = ts[o];
    ls += t; lss += t * t;
  }
  ls = wred(ls); lss = wred(lss);
  if (lane == 0) { red2[wid][0] = ls; red2[wid][1] = lss; }
  __syncthreads();
  if (tid == 0) {
    float S = red2[0][0] + red2[1][0] + red2[2][0] + red2[3][0];
    float SS = red2[0][1] + red2[1][1] + red2[2][1] + red2[3][1];
    float m = S * (1.f / 1024.f);
    float var = SS * (1.f / 1024.f) - m * m;
    bc[0] = m; bc[1] = rsqrtf(var + EPSF);
  }
  __syncthreads();
  const float m = bc[0], inv = bc[1];
  for (int o = tid; o < 1024; o += 256) {
    float y = fmaf((ts[o] - m) * inv, lng[o], lnb[o]);
    float e = (y > 0.f) ? y : expm1f(y);
    ts[o] = hs[o] + e;  // h2
  }
  __syncthreads();
  if (tid < 192) {
    int e = tid >> 2, part = tid & 3;
    float acc = 0.f;
    const float* wr = f2w + e * 1024 + part * 4;
    for (int i = 0; i < 64; ++i) {
      float4 wv = *(const float4*)(wr + i * 16);
      int ob = i * 16 + part * 4;
      acc = fmaf(wv.x, ts[ob], fmaf(wv.y, ts[ob + 1], fmaf(wv.z, ts[ob + 2], fmaf(wv.w, ts[ob + 3], acc))));
    }
    acc += __shfl_down(acc, 1, 64);
    acc += __shfl_down(acc, 2, 64);
    if (part == 0) mw_s[e] = acc + f2b[e];
  }
  __syncthreads();
  if (tid < 64) {
    float v = (tid < 48) ? mw_s[tid] : 0.f;
    float t = wred(v);
    if (tid == 0) tot_s = t;
  }
  __syncthreads();
  if (tid < 48) {
    float wg = mw_s[tid] / tot_s;
    mw_s[tid] = wg;
    wgate[b * 48 + tid] = wg;
  }
  __syncthreads();
  if (tid < 32) {
    const int o = tid;
    const float v0 = vp[b * 3], v1 = vp[b * 3 + 1], v2 = vp[b * 3 + 2];
    float acc = 0.f;
#pragma unroll 4
    for (int e = 0; e < 48; ++e) {
      const float* wr = w0 + (e * 32 + o) * 3;
      float y = b0[e * 32 + o] + wr[0] * v0 + wr[1] * v1 + wr[2] * v2;
      acc = fmaf(mw_s[e], y, acc);
    }
    s1pre[b * 32 + o] = acc;
  }
}

// ---------------- moe1 (b x expert-chunk): bn over batch (redundant) + prelu + partial gated sum ----------------
// grid 256 = 32 b x 8 chunks of 6 experts; pmoe[ech][b][op] partials, reduced in k_final.
__global__ __launch_bounds__(128) void k_moe1(
    const float* __restrict__ s1pre, const float* __restrict__ g0,
    const float* __restrict__ be0, const float* __restrict__ pf_p,
    const float* __restrict__ wgate, const float* __restrict__ w1,
    const float* __restrict__ b1, float* __restrict__ pmoe) {
  __shared__ float s1n[32];
  __shared__ float wgs[6];
  const int tid = threadIdx.x;
  const int b = blockIdx.x >> 3, ech = blockIdx.x & 7;
  const int e0 = ech * 6;
  const float pf = pf_p[0];
  if (tid < 6) wgs[tid] = wgate[b * 48 + e0 + tid];
  if (tid < 32) {
    const int o = tid;
    float s = 0.f, ss = 0.f;
    for (int bb = 0; bb < 32; ++bb) {
      float v = s1pre[bb * 32 + o];
      s += v; ss += v * v;
    }
    float mm = s * (1.f / 32.f);
    float var = ss * (1.f / 32.f) - mm * mm;
    float a = g0[o] * rsqrtf(var + EPSF);
    float c = be0[o] - mm * a;
    float v = fmaf(s1pre[b * 32 + o], a, c);
    s1n[o] = (v >= 0.f) ? v : pf * v;
  }
  __syncthreads();
  const int op = tid;  // 0..127
  float acc = 0.f;
#pragma unroll
  for (int ee = 0; ee < 6; ++ee) {
    const int e = e0 + ee;
    const float* wr = w1 + (e * 128 + op) * 32;
    float y = b1[e * 128 + op];
#pragma unroll
    for (int i = 0; i < 32; i += 4) {
      float4 wv = *(const float4*)(wr + i);
      y = fmaf(wv.x, s1n[i], fmaf(wv.y, s1n[i + 1], fmaf(wv.z, s1n[i + 2], fmaf(wv.w, s1n[i + 3], y))));
    }
    acc = fmaf(wgs[ee], y, acc);
  }
  pmoe[ech * 4096 + b * 128 + op] = acc;
}

// ---------------- final: reduce 8 moe partials; bn over batch + prelu + dot(128) + sigmoid ----------------
__global__ __launch_bounds__(256) void k_final(
    const float* __restrict__ pmoe, const float* __restrict__ g1,
    const float* __restrict__ be1, const float* __restrict__ pf_p,
    const float* __restrict__ ow, const float* __restrict__ obp,
    float* __restrict__ outp) {
  __shared__ float s2[32 * 132];
  __shared__ float ca[128], cb[128];
  const int tid = threadIdx.x;
  for (int r = tid; r < 4096; r += 256) {
    int b = r >> 7, o = r & 127;
    float v = 0.f;
#pragma unroll
    for (int j = 0; j < 8; ++j) v += pmoe[j * 4096 + r];
    s2[b * 132 + o] = v;
  }
  __syncthreads();
  if (tid < 128) {
    const int o = tid;
    float s = 0.f, ss = 0.f;
    for (int b = 0; b < 32; ++b) {
      float v = s2[b * 132 + o];
      s += v; ss += v * v;
    }
    float mm = s * (1.f / 32.f);
    float var = ss * (1.f / 32.f) - mm * mm;
    float a = g1[o] * rsqrtf(var + EPSF);
    ca[o] = a; cb[o] = be1[o] - mm * a;
  }
  __syncthreads();
  const float pf = pf_p[0];
  if (tid < 32) {
    const int b = tid;
    float acc = 0.f;
#pragma unroll 4
    for (int o = 0; o < 128; ++o) {
      float v = fmaf(s2[b * 132 + o], ca[o], cb[o]);
      v = (v >= 0.f) ? v : pf * v;
      acc = fmaf(v, ow[o], acc);
    }
    float z = acc + obp[0];
    outp[b] = 1.f / (1.f + __expf(-z));
  }
}

// ---------------- launch ----------------
extern "C" void kernel_launch(void* const* d_in, const int* in_sizes, int n_in,
                              void* d_out, int out_size, void* d_ws, size_t ws_size,
                              hipStream_t stream) {
  (void)in_sizes; (void)n_in; (void)out_size; (void)ws_size;
  const float* vertex_pos = (const float*)d_in[0];
  const float* body_mesh  = (const float*)d_in[1];
  const float* conv1_w    = (const float*)d_in[2];
  const float* conv1_b    = (const float*)d_in[3];
  const float* bn1_g      = (const float*)d_in[4];
  const float* bn1_b      = (const float*)d_in[5];
  const float* conv2_w    = (const float*)d_in[6];
  const float* conv2_b    = (const float*)d_in[7];
  const float* bn2_g      = (const float*)d_in[8];
  const float* bn2_b      = (const float*)d_in[9];
  const float* prelu_a    = (const float*)d_in[10];
  const float* wq = (const float*)d_in[11]; const float* bq = (const float*)d_in[12];
  const float* wk = (const float*)d_in[13]; const float* bk = (const float*)d_in[14];
  const float* wv = (const float*)d_in[15]; const float* bv = (const float*)d_in[16];
  const float* fc_w  = (const float*)d_in[17]; const float* fc_b  = (const float*)d_in[18];
  const float* ff1_w = (const float*)d_in[19]; const float* ff1_b = (const float*)d_in[20];
  const float* ln_g  = (const float*)d_in[21]; const float* ln_b  = (const float*)d_in[22];
  const float* ff2_w = (const float*)d_in[23]; const float* ff2_b = (const float*)d_in[24];
  const float* fus_w0 = (const float*)d_in[25]; const float* fus_b0 = (const float*)d_in[26];
  const float* fus_w1 = (const float*)d_in[27]; const float* fus_b1 = (const float*)d_in[28];
  const float* bnf0_g = (const float*)d_in[29]; const float* bnf0_b = (const float*)d_in[30];
  const float* bnf1_g = (const float*)d_in[31]; const float* bnf1_b = (const float*)d_in[32];
  const float* prelu_f = (const float*)d_in[33];
  const float* out_w = (const float*)d_in[34]; const float* out_b = (const float*)d_in[35];

  float* ws = (float*)d_ws;
  float* conv1_out = ws + 0;        // 326496
  float* conv2_out = ws + 326496;   // -> 621408
  float* qws = ws + 621408;         // -> 752480
  float* kws = ws + 752480;         // -> 883552
  float* vws = ws + 883552;         // -> 1014624
  float* p_fc = ws + 0;             // 1048576 (overlays region A; dead by k_fc)
  float* av    = ws + 1048576;      // -> 1179648
  float* hbuf  = ws + 1179648;      // -> 1212416
  float* p_ff1 = ws + 1212416;      // -> 1736704
  float* part1 = ws + 1736704;      // 6*448 -> 1741888 (padded)
  float* part2 = ws + 1741888;      // 6*192 -> 1746496
  float* wgate = ws + 1746496;      // -> 1748032
  float* s1pre = ws + 1748032;      // -> 1749056
  float* pmoe  = ws + 1749056;      // 8*4096 -> 1781824
  float* wTg   = ws + 1781824;      // 3888 -> 1785712 floats (~7.1 MB)

  k_wprep<<<16, 256, 0, stream>>>(conv1_w, wTg);
  k_conv1<<<448, 256, 0, stream>>>(body_mesh, wTg, conv1_b, conv1_out, part1);
  k_conv2<<<192, 256, 0, stream>>>(conv1_out, part1, bn1_g, bn1_b, conv2_w, conv2_b, conv2_out, part2);
  k_qkv<<<128, 256, 0, stream>>>(conv2_out, part2, bn2_g, bn2_b, prelu_a,
                                 wq, bq, wk, bk, wv, bv, qws, kws, vws);
  k_attn<<<512, 256, 0, stream>>>(qws, kws, vws, av);
  k_fc<<<512, 256, 0, stream>>>(av, fc_w, p_fc);
  k_hred<<<128, 256, 0, stream>>>(p_fc, fc_b, hbuf);
  k_ff1<<<256, 256, 0, stream>>>(hbuf, ff1_w, p_ff1);
  k_tail1<<<32, 256, 0, stream>>>(hbuf, p_ff1, ff1_b, ln_g, ln_b, ff2_w, ff2_b,
                                  vertex_pos, fus_w0, fus_b0, wgate, s1pre);
  k_moe1<<<256, 128, 0, stream>>>(s1pre, bnf0_g, bnf0_b, prelu_f, wgate, fus_w1, fus_b1, pmoe);
  k_final<<<1, 256, 0, stream>>>(pmoe, bnf1_g, bnf1_b, prelu_f, out_w, out_b, (float*)d_out);
}